// Round 15
// baseline (1293.756 us; speedup 1.0000x reference)
//
#include <hip/hip_runtime.h>

constexpr int kB   = 4;
constexpr int kNEG = 33;
constexpr int kN   = 10000;
constexpr int kR   = 256;
constexpr int kD   = 64;
constexpr int kL   = 6;
constexpr int kE   = 200000;
constexpr int kER  = 80000;

typedef const float* fp;
typedef __attribute__((ext_vector_type(8))) short bf16x8;
typedef __attribute__((ext_vector_type(4))) float f32x4;

__device__ __forceinline__ float rdlane(float v, int l) {
  return __uint_as_float(__builtin_amdgcn_readlane(__float_as_uint(v), l));
}
__device__ __forceinline__ float wave_sum64(float v) {
  #pragma unroll
  for (int o = 32; o > 0; o >>= 1) v += __shfl_xor(v, o, 64);
  return v;
}
__device__ __forceinline__ float group_sum16(float v) {
  #pragma unroll
  for (int o = 8; o > 0; o >>= 1) v += __shfl_xor(v, o, 64);
  return v;
}
__device__ __forceinline__ short f2bf(float x) {
  unsigned u = __float_as_uint(x);
  unsigned r = (u + 0x7fffu + ((u >> 16) & 1u)) >> 16;
  return (short)r;
}
__device__ __forceinline__ float bf2f_u(unsigned short s) {
  return __uint_as_float(((unsigned)s) << 16);
}
__device__ __forceinline__ float bf2f(short s) { return bf2f_u((unsigned short)s); }

// ---------------- utility ----------------
__global__ void k_fill(float* __restrict__ p, float v, int n) {
  int i = blockIdx.x * blockDim.x + threadIdx.x;
  int stride = gridDim.x * blockDim.x;
  for (; i < n; i += stride) p[i] = v;
}
__global__ void k_zero_i(int* __restrict__ p, int n) {
  int i = blockIdx.x * blockDim.x + threadIdx.x;
  int stride = gridDim.x * blockDim.x;
  for (; i < n; i += stride) p[i] = 0;
}
__global__ void k_add_row(float* __restrict__ dst, const int* __restrict__ batch) {
  int tid = threadIdx.x;
  int b = tid >> 6, d = tid & 63;
  int row = batch[b * kNEG * 3 + 2];
  dst[((size_t)b * kR + row) * 64 + d] += 1.0f;
}
__global__ void k_add_row_ent(float* __restrict__ dst, const int* __restrict__ batch,
                              const float* __restrict__ q) {
  int tid = threadIdx.x;
  int b = tid >> 6, d = tid & 63;
  int row = batch[b * kNEG * 3];
  dst[((size_t)b * kN + row) * 64 + d] += q[b * 64 + d];
}
__global__ void k_get_q(float* __restrict__ q, const float* __restrict__ relx,
                        const int* __restrict__ batch) {
  int tid = threadIdx.x;
  int b = tid >> 6, d = tid & 63;
  int r0 = batch[b * kNEG * 3 + 2];
  q[b * 64 + d] = relx[((size_t)b * kR + r0) * 64 + d];
}

// ---------------- CSR build ----------------
__global__ void k_hist(const int* __restrict__ dst, int ne, int* __restrict__ cnt) {
  int i = blockIdx.x * blockDim.x + threadIdx.x;
  if (i < ne) atomicAdd(&cnt[dst[i]], 1);
}
__global__ void k_fill_csr(const int* __restrict__ src, const int* __restrict__ dst,
                           const int* __restrict__ et, int ne,
                           int* __restrict__ cursor, int2* __restrict__ out) {
  int i = blockIdx.x * blockDim.x + threadIdx.x;
  if (i < ne) {
    int p = atomicAdd(&cursor[dst[i]], 1);
    out[p] = make_int2(src[i], et[i]);
  }
}
__global__ void k_hist_rel_lds(const int* __restrict__ rel_dst, int* __restrict__ cnt) {
  int g = blockIdx.y;
  __shared__ int lc[256];
  lc[threadIdx.x] = 0;
  __syncthreads();
  int lo = blockIdx.x * 8000, hi = min(lo + 8000, kER);
  for (int e = lo + threadIdx.x; e < hi; e += 256)
    atomicAdd(&lc[rel_dst[(size_t)g * kER + e]], 1);
  __syncthreads();
  int c = lc[threadIdx.x];
  if (c) atomicAdd(&cnt[g * 256 + threadIdx.x], c);
}
__global__ void k_fill_rel_lds(const int* __restrict__ src, const int* __restrict__ dst,
                               const int* __restrict__ et,
                               int* __restrict__ cursor, int2* __restrict__ out) {
  int g = blockIdx.y;
  __shared__ int lc[256];
  lc[threadIdx.x] = 0;
  __syncthreads();
  int lo = blockIdx.x * 8000, hi = min(lo + 8000, kER);
  const int* db = dst + (size_t)g * kER;
  for (int e = lo + threadIdx.x; e < hi; e += 256)
    atomicAdd(&lc[db[e]], 1);
  __syncthreads();
  int c = lc[threadIdx.x];
  __syncthreads();
  lc[threadIdx.x] = c ? atomicAdd(&cursor[g * 257 + threadIdx.x], c) : 0;
  __syncthreads();
  for (int e = lo + threadIdx.x; e < hi; e += 256) {
    int bin = db[e];
    int p = atomicAdd(&lc[bin], 1);
    out[(size_t)g * kER + p] = make_int2(src[(size_t)g * kER + e], et[(size_t)g * kER + e]);
  }
}
__global__ void k_scan_multi(const int* __restrict__ cnt, int* __restrict__ start,
                             int* __restrict__ cursor, int n, int cstride, int sstride) {
  const int* c = cnt + (size_t)blockIdx.x * cstride;
  int* st = start + (size_t)blockIdx.x * sstride;
  int* cu = cursor + (size_t)blockIdx.x * sstride;
  __shared__ int part[256];
  int t = threadIdx.x;
  int chunk = (n + 255) / 256;
  int lo = t * chunk, hi = min(lo + chunk, n);
  int s = 0;
  for (int i = lo; i < hi; ++i) s += c[i];
  part[t] = s;
  __syncthreads();
  if (t == 0) { int run = 0; for (int i = 0; i < 256; ++i) { int v = part[i]; part[i] = run; run += v; } }
  __syncthreads();
  int run = part[t];
  for (int i = lo; i < hi; ++i) { st[i] = run; cu[i] = run; run += c[i]; }
  if (t == 255) st[n] = run;
}

// ---------------- weight packing (MFMA B-frag order, bf16 hi/lo) ----------------
__global__ void k_packw(const float* __restrict__ w1, const float* __restrict__ w2,
                        short* __restrict__ w1h, short* __restrict__ w1l,
                        short* __restrict__ w2h, short* __restrict__ w2l) {
  int pg = blockIdx.x;
  for (int i = threadIdx.x; i < 4096; i += 256) {
    int t = i & 7, lane = (i >> 3) & 63, nt = (i >> 9) & 3, ks = i >> 11;
    int mr = lane & 15, kg = lane >> 4;
    int src = pg * 4096 + (ks * 32 + kg * 8 + t) * 64 + nt * 16 + mr;
    int dst = pg * 4096 + i;
    float v1 = w1[src]; short h1 = f2bf(v1);
    w1h[dst] = h1; w1l[dst] = f2bf(v1 - bf2f(h1));
    float v2 = w2[src]; short h2 = f2bf(v2);
    w2h[dst] = h2; w2l[dst] = f2bf(v2 - bf2f(h2));
  }
}
__global__ void k_packw_e(const float* __restrict__ w, short* __restrict__ wh, short* __restrict__ wl) {
  int set = blockIdx.x;
  for (int i = threadIdx.x; i < 8192; i += 256) {
    int t = i & 7, lane = (i >> 3) & 63, nt = (i >> 9) & 3, ks = i >> 11;
    int mr = lane & 15, kg = lane >> 4;
    int src = set * 8192 + (ks * 32 + kg * 8 + t) * 64 + nt * 16 + mr;
    int dst = set * 8192 + i;
    float v = w[src]; short h = f2bf(v);
    wh[dst] = h; wl[dst] = f2bf(v - bf2f(h));
  }
}

// ---------------- MFMA gate MLP (split-bf16), bf16 out in [g][b*kN+n][d] ----------------
__global__ void __launch_bounds__(256) k_mlp_mfma(
    const float* __restrict__ in, const short* __restrict__ w1h, const short* __restrict__ w1l,
    const float* __restrict__ b1, const short* __restrict__ w2h, const short* __restrict__ w2l,
    const float* __restrict__ b2, int layer, unsigned short* __restrict__ out) {
  int g = blockIdx.y;
  int pg = g * kL + layer;
  int w = threadIdx.x >> 6, lane = threadIdx.x & 63;
  int mrow = lane & 15, kgrp = lane >> 4;
  int r0 = blockIdx.x * 64 + w * 16;
  __shared__ float hbuf[4][16][68];
  const float* xp = in + (size_t)(r0 + mrow) * 64 + kgrp * 8;
  bf16x8 a1h[2], a1l[2];
  #pragma unroll
  for (int ks = 0; ks < 2; ++ks) {
    #pragma unroll
    for (int t = 0; t < 8; ++t) {
      float v = xp[ks * 32 + t];
      short h = f2bf(v); a1h[ks][t] = h; a1l[ks][t] = f2bf(v - bf2f(h));
    }
  }
  const bf16x8* B1h = (const bf16x8*)(w1h + (size_t)pg * 4096);
  const bf16x8* B1l = (const bf16x8*)(w1l + (size_t)pg * 4096);
  #pragma unroll
  for (int nt = 0; nt < 4; ++nt) {
    f32x4 c = {0.f, 0.f, 0.f, 0.f};
    #pragma unroll
    for (int ks = 0; ks < 2; ++ks) {
      bf16x8 bh = B1h[(ks * 4 + nt) * 64 + lane];
      bf16x8 bl = B1l[(ks * 4 + nt) * 64 + lane];
      c = __builtin_amdgcn_mfma_f32_16x16x32_bf16(a1h[ks], bh, c, 0, 0, 0);
      c = __builtin_amdgcn_mfma_f32_16x16x32_bf16(a1h[ks], bl, c, 0, 0, 0);
      c = __builtin_amdgcn_mfma_f32_16x16x32_bf16(a1l[ks], bh, c, 0, 0, 0);
    }
    int col = nt * 16 + mrow;
    float bv = b1[pg * 64 + col];
    #pragma unroll
    for (int rg = 0; rg < 4; ++rg)
      hbuf[w][kgrp * 4 + rg][col] = fmaxf(c[rg] + bv, 0.f);
  }
  __syncthreads();
  bf16x8 a2h[2], a2l[2];
  #pragma unroll
  for (int ks = 0; ks < 2; ++ks) {
    #pragma unroll
    for (int t = 0; t < 8; ++t) {
      float v = hbuf[w][mrow][ks * 32 + kgrp * 8 + t];
      short h = f2bf(v); a2h[ks][t] = h; a2l[ks][t] = f2bf(v - bf2f(h));
    }
  }
  const bf16x8* B2h = (const bf16x8*)(w2h + (size_t)pg * 4096);
  const bf16x8* B2l = (const bf16x8*)(w2l + (size_t)pg * 4096);
  unsigned short* ob = out + (size_t)g * kB * kN * 64;
  #pragma unroll
  for (int nt = 0; nt < 4; ++nt) {
    f32x4 c = {0.f, 0.f, 0.f, 0.f};
    #pragma unroll
    for (int ks = 0; ks < 2; ++ks) {
      bf16x8 bh = B2h[(ks * 4 + nt) * 64 + lane];
      bf16x8 bl = B2l[(ks * 4 + nt) * 64 + lane];
      c = __builtin_amdgcn_mfma_f32_16x16x32_bf16(a2h[ks], bh, c, 0, 0, 0);
      c = __builtin_amdgcn_mfma_f32_16x16x32_bf16(a2h[ks], bl, c, 0, 0, 0);
      c = __builtin_amdgcn_mfma_f32_16x16x32_bf16(a2l[ks], bh, c, 0, 0, 0);
    }
    int col = nt * 16 + mrow;
    float bv = b2[pg * 64 + col];
    #pragma unroll
    for (int rg = 0; rg < 4; ++rg) {
      int grow = r0 + kgrp * 4 + rg;          // = b*kN + n
      ob[(size_t)grow * 64 + col] = (unsigned short)f2bf(c[rg] + bv);
    }
  }
}

// ---------------- rel-gate MLP for entity phase: fp32 out [j][b][r][d] ----------------
__global__ void __launch_bounds__(256) k_mlp_rel6(
    const float* __restrict__ in, fp p1w, fp p1b, fp p2w, fp p2b,
    float* __restrict__ out) {
  int j = blockIdx.y;
  int row = blockIdx.x * 4 + (threadIdx.x >> 6);   // = b*256 + r
  int lane = threadIdx.x & 63;
  fp W1 = p1w + (size_t)j * 4096;
  fp W2 = p2w + (size_t)j * 4096;
  float xv = in[(size_t)row * 64 + lane];
  float a = p1b[j * 64 + lane];
  float wbuf[8];
  #pragma unroll
  for (int kk = 0; kk < 64; kk += 8) {
    #pragma unroll
    for (int u = 0; u < 8; ++u) wbuf[u] = W1[(kk + u) * 64 + lane];
    #pragma unroll
    for (int u = 0; u < 8; ++u) a = fmaf(rdlane(xv, kk + u), wbuf[u], a);
  }
  a = fmaxf(a, 0.f);
  float c = p2b[j * 64 + lane];
  #pragma unroll
  for (int kk = 0; kk < 64; kk += 8) {
    #pragma unroll
    for (int u = 0; u < 8; ++u) wbuf[u] = W2[(kk + u) * 64 + lane];
    #pragma unroll
    for (int u = 0; u < 8; ++u) c = fmaf(rdlane(a, kk + u), wbuf[u], c);
  }
  out[((size_t)j * kB * kR + row) * 64 + lane] = c;
}

// ---------------- i=0 rel specials ----------------
__global__ void k_gate0(fp p1w, fp p1b, fp p2w, fp p2b, float* __restrict__ gate0) {
  int g = threadIdx.x >> 6, lane = threadIdx.x & 63;
  int pg = g * kL;
  float a = p1b[pg * 64 + lane];
  #pragma unroll
  for (int k = 0; k < 64; ++k) a += p1w[(size_t)pg * 4096 + k * 64 + lane];
  a = fmaxf(a, 0.f);
  float c = p2b[pg * 64 + lane];
  #pragma unroll
  for (int k = 0; k < 64; ++k)
    c = fmaf(rdlane(a, k), p2w[(size_t)pg * 4096 + k * 64 + lane], c);
  gate0[g * 64 + lane] = c;
}
__global__ void k_rel_agg0(const int* __restrict__ rel_start, const int2* __restrict__ rel_edges,
                           const int* __restrict__ batch, const float* __restrict__ gate0,
                           float* __restrict__ agg) {
  int wid = (blockIdx.x * blockDim.x + threadIdx.x) >> 6;
  int lane = threadIdx.x & 63;
  int g = wid >> 10, rem = wid & 1023, b = rem >> 8, r = rem & 255;
  int r0 = batch[b * kNEG * 3 + 2];
  const int* start = rel_start + g * 257;
  const int2* edges = rel_edges + (size_t)g * kER;
  int s0 = start[r], s1 = start[r + 1];
  int cnt = 0;
  for (int base = s0; base < s1; base += 64) {
    int e = base + lane;
    bool m = false;
    if (e < s1) m = (edges[e].x == r0);
    cnt += (int)__popcll(__ballot(m));
  }
  agg[(size_t)wid * 64 + lane] = gate0[g * 64 + lane] * (float)cnt + ((r == r0) ? 1.f : 0.f);
}

// ---------------- rel gather: block i = r*16 + (g,b); slice (g,b) -> XCD s%8 ----------------
// gate bf16 [g][b][n][d] (1.28 MB/slice, L2-resident); x = rel_x fp32 [b][r][d] (64 KB)
__global__ void __launch_bounds__(256) k_gather_rel_b(
    const float* __restrict__ rel_x, const unsigned short* __restrict__ gateN,
    const int* __restrict__ rel_start, const int2* __restrict__ rel_edges,
    const int* __restrict__ batch, float* __restrict__ agg) {
  int i = blockIdx.x;                  // 4096
  int s = i & 15, r = i >> 4;
  int g = s >> 2, b = s & 3;
  const unsigned short* gate = gateN + ((size_t)(g * kB + b) * kN) * 64;
  const float* xb = rel_x + (size_t)b * kR * 64;
  const int* start = rel_start + g * 257;
  const int2* edges = rel_edges + (size_t)g * kER;
  int w = threadIdx.x >> 6, lane = threadIdx.x & 63;
  int s0 = start[r], s1 = start[r + 1];
  int len = s1 - s0;
  int per = (len + 3) >> 2;
  int e0 = s0 + w * per, e1 = min(e0 + per, s1);
  float acc = 0.f;
  int2 se;
  if (e0 < e1) se = edges[e0];
  for (int e = e0; e < e1; ++e) {
    int2 cur = se;
    if (e + 1 < e1) se = edges[e + 1];
    acc = fmaf(xb[(size_t)cur.x * 64 + lane], bf2f_u(gate[(size_t)cur.y * 64 + lane]), acc);
  }
  __shared__ float red[4][64];
  red[w][lane] = acc;
  __syncthreads();
  if (w == 0) {
    float a = red[0][lane] + red[1][lane] + red[2][lane] + red[3][lane];
    int r0b = batch[b * kNEG * 3 + 2];
    if (r == r0b) a += 1.0f;
    agg[(((size_t)g * kB + b) * kR + r) * 64 + lane] = a;
  }
}

// ---------------- rel conv partial: grid (64, g) ----------------
__global__ void __launch_bounds__(256) k_conv_rel3(
    const float* __restrict__ rel_x, float* __restrict__ agg,
    fp rlw, fp rlb, fp rlns, fp rlnb, int layer) {
  int g = blockIdx.y;
  int pg = g * kL + layer;
  int wave = threadIdx.x >> 6, lane = threadIdx.x & 63;
  int row0 = blockIdx.x * 16 + wave * 4;
  const float* xp = rel_x + (size_t)row0 * 64 + lane;
  float* ap = agg + ((size_t)g * 1024 + row0) * 64 + lane;
  float x0 = xp[0], x1 = xp[64], x2 = xp[128], x3 = xp[192];
  float g0 = ap[0], g1 = ap[64], g2 = ap[128], g3 = ap[192];
  fp w1 = rlw + (size_t)pg * 8192;
  float bv = rlb[pg * 64 + lane];
  float o0 = bv, o1 = bv, o2 = bv, o3 = bv;
  float wbuf[8];
  #pragma unroll
  for (int kk = 0; kk < 128; kk += 8) {
    #pragma unroll
    for (int u = 0; u < 8; ++u) wbuf[u] = w1[(kk + u) * 64 + lane];
    #pragma unroll
    for (int u = 0; u < 8; ++u) {
      int k = kk + u; float w = wbuf[u];
      if (k < 64) {
        o0 = fmaf(rdlane(x0, k), w, o0); o1 = fmaf(rdlane(x1, k), w, o1);
        o2 = fmaf(rdlane(x2, k), w, o2); o3 = fmaf(rdlane(x3, k), w, o3);
      } else {
        o0 = fmaf(rdlane(g0, k - 64), w, o0); o1 = fmaf(rdlane(g1, k - 64), w, o1);
        o2 = fmaf(rdlane(g2, k - 64), w, o2); o3 = fmaf(rdlane(g3, k - 64), w, o3);
      }
    }
  }
  float s = rlns[pg * 64 + lane], t = rlnb[pg * 64 + lane];
  { float m = wave_sum64(o0) * (1.f/64.f); float c = o0 - m;
    float v = wave_sum64(c*c) * (1.f/64.f);
    ap[0] = fmaxf(c * rsqrtf(v + 1e-5f) * s + t, 0.f); }
  { float m = wave_sum64(o1) * (1.f/64.f); float c = o1 - m;
    float v = wave_sum64(c*c) * (1.f/64.f);
    ap[64] = fmaxf(c * rsqrtf(v + 1e-5f) * s + t, 0.f); }
  { float m = wave_sum64(o2) * (1.f/64.f); float c = o2 - m;
    float v = wave_sum64(c*c) * (1.f/64.f);
    ap[128] = fmaxf(c * rsqrtf(v + 1e-5f) * s + t, 0.f); }
  { float m = wave_sum64(o3) * (1.f/64.f); float c = o3 - m;
    float v = wave_sum64(c*c) * (1.f/64.f);
    ap[192] = fmaxf(c * rsqrtf(v + 1e-5f) * s + t, 0.f); }
}

// rel_x += sum_g y[g]
__global__ void k_sum_rel(float* __restrict__ rel_x, const float* __restrict__ y) {
  int i = blockIdx.x * blockDim.x + threadIdx.x;   // 65536
  rel_x[i] += y[i] + y[65536 + i] + y[131072 + i] + y[196608 + i];
}

// ---------------- ent gather: wave = (b, node); b -> XCD pair {2b,2b+1}; all fp32 ----------------
// gateL fp32 [b][r][d] (64 KB/b); xcur fp32 [b][n][d] (2.56 MB/b); agg [b][n][d]
template<bool FIRST>
__global__ void __launch_bounds__(256) k_ent_gather_b(
    const float* __restrict__ xcur, const float* __restrict__ gateL,
    const int* __restrict__ start, const int2* __restrict__ edges,
    const float* __restrict__ q, const int* __restrict__ batch,
    float* __restrict__ agg) {
  int i = blockIdx.x;                 // 10000
  int rr = i & 7, m = i >> 3;         // m in [0,1250)
  int b = rr >> 1, p = rr & 1;
  int w = threadIdx.x >> 6, lane = threadIdx.x & 63;
  int n = ((m * 2 + p) << 2) + w;     // node 0..9999
  int h0 = batch[b * kNEG * 3];
  float qv = q[b * 64 + lane];
  const float* xb = xcur + (size_t)b * kN * 64;
  const float* gb = gateL + (size_t)b * kR * 64;
  float a = 0.f;
  int s0 = start[n], s1 = start[n + 1];
  int2 se;
  if (s0 < s1) se = edges[s0];
  for (int e = s0; e < s1; ++e) {
    int2 cur = se;
    if (e + 1 < s1) se = edges[e + 1];
    float gv = gb[(size_t)cur.y * 64 + lane];
    if (FIRST) {
      if (cur.x == h0) a = fmaf(qv, gv, a);
    } else {
      a = fmaf(xb[(size_t)cur.x * 64 + lane], gv, a);
    }
  }
  if (n == h0) a += qv;
  agg[(size_t)b * kN * 64 + (size_t)n * 64 + lane] = a;
}

// ---------------- ent conv via MFMA ----------------
__global__ void __launch_bounds__(256) k_ent_conv_mfma(
    const float* __restrict__ xcur, const float* __restrict__ aggv,
    float* __restrict__ xnext,
    const short* __restrict__ wh, const short* __restrict__ wl, int set,
    fp lb, fp lns, fp lnb) {
  int w = threadIdx.x >> 6, lane = threadIdx.x & 63;
  int mrow = lane & 15, kgrp = lane >> 4;
  int r0 = blockIdx.x * 64 + w * 16;
  int arow = r0 + mrow;
  bf16x8 ah[4], al[4];
  #pragma unroll
  for (int ks = 0; ks < 4; ++ks) {
    const float* p = (ks < 2) ? (xcur + (size_t)arow * 64 + ks * 32 + kgrp * 8)
                              : (aggv + (size_t)arow * 64 + (ks - 2) * 32 + kgrp * 8);
    #pragma unroll
    for (int t = 0; t < 8; ++t) {
      float v = p[t];
      short h = f2bf(v); ah[ks][t] = h; al[ks][t] = f2bf(v - bf2f(h));
    }
  }
  const bf16x8* Bh = (const bf16x8*)(wh + (size_t)set * 8192);
  const bf16x8* Bl = (const bf16x8*)(wl + (size_t)set * 8192);
  float o[4][4];
  #pragma unroll
  for (int nt = 0; nt < 4; ++nt) {
    f32x4 c = {0.f, 0.f, 0.f, 0.f};
    #pragma unroll
    for (int ks = 0; ks < 4; ++ks) {
      bf16x8 bh = Bh[(ks * 4 + nt) * 64 + lane];
      bf16x8 bl = Bl[(ks * 4 + nt) * 64 + lane];
      c = __builtin_amdgcn_mfma_f32_16x16x32_bf16(ah[ks], bh, c, 0, 0, 0);
      c = __builtin_amdgcn_mfma_f32_16x16x32_bf16(ah[ks], bl, c, 0, 0, 0);
      c = __builtin_amdgcn_mfma_f32_16x16x32_bf16(al[ks], bh, c, 0, 0, 0);
    }
    float bv = lb[nt * 16 + mrow];
    #pragma unroll
    for (int rg = 0; rg < 4; ++rg) o[nt][rg] = c[rg] + bv;
  }
  float mean[4], varr[4];
  #pragma unroll
  for (int rg = 0; rg < 4; ++rg) {
    float p = o[0][rg] + o[1][rg] + o[2][rg] + o[3][rg];
    mean[rg] = group_sum16(p) * (1.f / 64.f);
    float d0 = o[0][rg] - mean[rg], d1 = o[1][rg] - mean[rg];
    float d2 = o[2][rg] - mean[rg], d3 = o[3][rg] - mean[rg];
    float vs = d0 * d0 + d1 * d1 + d2 * d2 + d3 * d3;
    varr[rg] = group_sum16(vs) * (1.f / 64.f);
  }
  #pragma unroll
  for (int nt = 0; nt < 4; ++nt) {
    int col = nt * 16 + mrow;
    float s = lns[col], tt = lnb[col];
    #pragma unroll
    for (int rg = 0; rg < 4; ++rg) {
      int grow = r0 + kgrp * 4 + rg;
      float xv = xcur[(size_t)grow * 64 + col];
      float y = xv + fmaxf((o[nt][rg] - mean[rg]) * rsqrtf(varr[rg] + 1e-5f) * s + tt, 0.f);
      xnext[(size_t)grow * 64 + col] = y;
    }
  }
}

// ---------------- node_reps = concat(ent_x, q)@nmw + nmb ----------------
__global__ void __launch_bounds__(256) k_nodeup4(
    const float* __restrict__ x, const float* __restrict__ q,
    fp nmw, fp nmb, float* __restrict__ out) {
  int wid = (blockIdx.x * blockDim.x + threadIdx.x) >> 6;
  int lane = threadIdx.x & 63;
  int r0 = wid * 4;
  if (r0 >= kB * kN) return;
  int b = r0 / kN;
  const float* ip = x + (size_t)r0 * 64 + lane;
  float x0 = ip[0], x1 = ip[64], x2 = ip[128], x3 = ip[192];
  float qv = q[b * 64 + lane];
  float bv = nmb[lane];
  float c0 = bv, c1 = bv, c2 = bv, c3 = bv;
  float wbuf[4];
  #pragma unroll
  for (int kk = 0; kk < 64; kk += 4) {
    #pragma unroll
    for (int u = 0; u < 4; ++u) wbuf[u] = nmw[(kk + u) * 64 + lane];
    #pragma unroll
    for (int u = 0; u < 4; ++u) {
      int k = kk + u; float w = wbuf[u];
      c0 = fmaf(rdlane(x0, k), w, c0); c1 = fmaf(rdlane(x1, k), w, c1);
      c2 = fmaf(rdlane(x2, k), w, c2); c3 = fmaf(rdlane(x3, k), w, c3);
    }
  }
  float qa = 0.f;
  #pragma unroll
  for (int k = 0; k < 64; ++k)
    qa = fmaf(rdlane(qv, k), nmw[(64 + k) * 64 + lane], qa);
  float* op = out + (size_t)r0 * 64 + lane;
  op[0] = c0 + qa; op[64] = c1 + qa; op[128] = c2 + qa; op[192] = c3 + qa;
}

// ---------------- final scoring ----------------
__global__ void k_score(const float* __restrict__ entx, const float* __restrict__ q,
                        const int* __restrict__ batch,
                        fp m1w, fp m1b, fp m2w, fp m2b,
                        float* __restrict__ out) {
  int b = blockIdx.x / kNEG, n = blockIdx.x % kNEG;
  int t = batch[(b * kNEG + n) * 3 + 1];
  int j = threadIdx.x;
  __shared__ float gv[128];
  __shared__ float red[2];
  gv[j] = (j < 64) ? entx[((size_t)b * kN + t) * 64 + j] : q[b * 64 + (j - 64)];
  __syncthreads();
  float acc = m1b[j];
  #pragma unroll 16
  for (int k = 0; k < 128; ++k)
    acc = fmaf(gv[k], m1w[k * 128 + j], acc);
  float h = fmaxf(acc, 0.f) * m2w[j];
  h = wave_sum64(h);
  if ((j & 63) == 0) red[j >> 6] = h;
  __syncthreads();
  if (j == 0) out[b * kNEG + n] = red[0] + red[1] + m2b[0];
}

// ---------------- host ----------------
extern "C" void kernel_launch(void* const* d_in, const int* in_sizes, int n_in,
                              void* d_out, int out_size, void* d_ws, size_t ws_size,
                              hipStream_t stream) {
  const int* edge_src  = (const int*)d_in[0];
  const int* edge_dst  = (const int*)d_in[1];
  const int* edge_type = (const int*)d_in[2];
  const int* rel_src   = (const int*)d_in[3];
  const int* rel_dst   = (const int*)d_in[4];
  const int* rel_etype = (const int*)d_in[5];
  const int* batch     = (const int*)d_in[6];
  fp e1p1w = (fp)d_in[7],  e1p1b = (fp)d_in[8],  e1p2w = (fp)d_in[9],  e1p2b = (fp)d_in[10];
  fp e1lw  = (fp)d_in[11], e1lb  = (fp)d_in[12], e1lns = (fp)d_in[13], e1lnb = (fp)d_in[14];
  fp e2p1w = (fp)d_in[15], e2p1b = (fp)d_in[16], e2p2w = (fp)d_in[17], e2p2b = (fp)d_in[18];
  fp e2lw  = (fp)d_in[19], e2lb  = (fp)d_in[20], e2lns = (fp)d_in[21], e2lnb = (fp)d_in[22];
  fp e2m1w = (fp)d_in[23], e2m1b = (fp)d_in[24], e2m2w = (fp)d_in[25], e2m2b = (fp)d_in[26];
  fp rp1w  = (fp)d_in[27], rp1b  = (fp)d_in[28], rp2w  = (fp)d_in[29], rp2b  = (fp)d_in[30];
  fp rlw   = (fp)d_in[31], rlb   = (fp)d_in[32], rlns  = (fp)d_in[33], rlnb  = (fp)d_in[34];
  fp nmw   = (fp)d_in[35], nmb   = (fp)d_in[36];

  float* ws = (float*)d_ws;
  float* rel_x     = ws;                           // 65,536 ([b][r][d])
  float* q         = rel_x + 65536;                // 256
  float* gate0     = q + 256;                      // 256
  float* gateR6f   = gate0 + 256;                  // 393,216 ([j][b][r][d] fp32)
  float* rel_agg   = gateR6f + 393216;             // 262,144 ([g][b][r][d])
  float* node_reps = rel_agg + 262144;             // 2,560,000
  float* ent_xa    = node_reps + 2560000;          // 2,560,000 ([b][n][d])
  float* ent_xb    = ent_xa + 2560000;             // 2,560,000
  float* ent_agg   = ent_xb + 2560000;             // 2,560,000 ([b][n][d])
  unsigned short* gateN = (unsigned short*)(ent_agg + 2560000);  // 10,240,000 ushorts ([g][b][n][d])
  int*   iws       = (int*)(gateN + 10240000);
  int2*  ent_edges = (int2*)iws;                   // 400,000 ints
  int2*  rel_edges = (int2*)(iws + 400000);        // 640,000 ints
  int*   ent_cnt   = iws + 400000 + 640000;        // 10,000
  int*   ent_start = ent_cnt + 10000;              // 10,001
  int*   ent_cur   = ent_start + 10001;            // 10,001
  int*   rel_cnt   = ent_cur + 10001;              // 1,024
  int*   rel_start = rel_cnt + 1024;               // 1,028
  int*   rel_cur   = rel_start + 1028;             // 1,028
  short* w1hp      = (short*)(rel_cur + 1028 + 2); // 98,304 shorts each
  short* w1lp      = w1hp + 98304;
  short* w2hp      = w1lp + 98304;
  short* w2lp      = w2hp + 98304;
  short* elwh      = w2lp + 98304;                 // 12*8192
  short* elwl      = elwh + 98304;

  const int nZero = 10000 + 10001 + 10001 + 1024;
  // ---- CSR build + weight packing ----
  k_zero_i<<<(nZero + 255) / 256, 256, 0, stream>>>(ent_cnt, nZero);
  k_hist<<<(kE + 255) / 256, 256, 0, stream>>>(edge_dst, kE, ent_cnt);
  k_hist_rel_lds<<<dim3(10, 4), 256, 0, stream>>>(rel_dst, rel_cnt);
  k_scan_multi<<<1, 256, 0, stream>>>(ent_cnt, ent_start, ent_cur, 10000, 0, 0);
  k_scan_multi<<<4, 256, 0, stream>>>(rel_cnt, rel_start, rel_cur, 256, 256, 257);
  k_fill_csr<<<(kE + 255) / 256, 256, 0, stream>>>(edge_src, edge_dst, edge_type, kE, ent_cur, ent_edges);
  k_fill_rel_lds<<<dim3(10, 4), 256, 0, stream>>>(rel_src, rel_dst, rel_etype, rel_cur, rel_edges);
  k_packw<<<24, 256, 0, stream>>>(rp1w, rp2w, w1hp, w1lp, w2hp, w2lp);
  k_packw_e<<<6, 256, 0, stream>>>(e1lw, elwh, elwl);
  k_packw_e<<<6, 256, 0, stream>>>(e2lw, elwh + 6 * 8192, elwl + 6 * 8192);

  // ---- rel_x = one-hot boundary ----
  k_fill<<<256, 256, 0, stream>>>(rel_x, 0.f, kB * kR * kD);
  k_add_row<<<1, 256, 0, stream>>>(rel_x, batch);

  // ---- i = 0 (node_reps == ones) ----
  k_gate0<<<1, 256, 0, stream>>>(rp1w, rp1b, rp2w, rp2b, gate0);
  k_rel_agg0<<<1024, 256, 0, stream>>>(rel_start, rel_edges, batch, gate0, rel_agg);
  k_conv_rel3<<<dim3(64, 4), 256, 0, stream>>>(rel_x, rel_agg, rlw, rlb, rlns, rlnb, 0);
  k_sum_rel<<<256, 256, 0, stream>>>(rel_x, rel_agg);

  // ---- entity_bf with e1 params -> node_reps ----
  k_get_q<<<1, 256, 0, stream>>>(q, rel_x, batch);
  k_mlp_rel6<<<dim3(256, 6), 256, 0, stream>>>(rel_x, e1p1w, e1p1b, e1p2w, e1p2b, gateR6f);
  k_fill<<<2048, 256, 0, stream>>>(ent_xa, 0.f, kB * kN * kD);
  k_add_row_ent<<<1, 256, 0, stream>>>(ent_xa, batch, q);
  {
    float* cur = ent_xa; float* nxt = ent_xb;
    for (int j = 0; j < kL; ++j) {
      const float* gL = gateR6f + (size_t)j * kB * kR * 64;
      if (j == 0)
        k_ent_gather_b<true><<<10000, 256, 0, stream>>>(cur, gL, ent_start, ent_edges, q, batch, ent_agg);
      else
        k_ent_gather_b<false><<<10000, 256, 0, stream>>>(cur, gL, ent_start, ent_edges, q, batch, ent_agg);
      k_ent_conv_mfma<<<625, 256, 0, stream>>>(cur, ent_agg, nxt, elwh, elwl, j,
          e1lb + (size_t)j * 64, e1lns + (size_t)j * 64, e1lnb + (size_t)j * 64);
      float* tf = cur; cur = nxt; nxt = tf;
    }
    k_nodeup4<<<2500, 256, 0, stream>>>(cur, q, nmw, nmb, node_reps);
  }

  // ---- i = 1..5 ----
  for (int i = 1; i < kL; ++i) {
    k_mlp_mfma<<<dim3(625, 4), 256, 0, stream>>>(node_reps, w1hp, w1lp, rp1b, w2hp, w2lp, rp2b, i, gateN);
    k_gather_rel_b<<<4096, 256, 0, stream>>>(rel_x, gateN, rel_start, rel_edges, batch, rel_agg);
    k_conv_rel3<<<dim3(64, 4), 256, 0, stream>>>(rel_x, rel_agg, rlw, rlb, rlns, rlnb, i);
    k_sum_rel<<<256, 256, 0, stream>>>(rel_x, rel_agg);
  }

  // ---- entity_bf with e2 params + scoring ----
  k_get_q<<<1, 256, 0, stream>>>(q, rel_x, batch);
  k_mlp_rel6<<<dim3(256, 6), 256, 0, stream>>>(rel_x, e2p1w, e2p1b, e2p2w, e2p2b, gateR6f);
  k_fill<<<2048, 256, 0, stream>>>(ent_xa, 0.f, kB * kN * kD);
  k_add_row_ent<<<1, 256, 0, stream>>>(ent_xa, batch, q);
  {
    float* cur = ent_xa; float* nxt = ent_xb;
    for (int j = 0; j < kL; ++j) {
      const float* gL = gateR6f + (size_t)j * kB * kR * 64;
      if (j == 0)
        k_ent_gather_b<true><<<10000, 256, 0, stream>>>(cur, gL, ent_start, ent_edges, q, batch, ent_agg);
      else
        k_ent_gather_b<false><<<10000, 256, 0, stream>>>(cur, gL, ent_start, ent_edges, q, batch, ent_agg);
      k_ent_conv_mfma<<<625, 256, 0, stream>>>(cur, ent_agg, nxt, elwh, elwl, 6 + j,
          e2lb + (size_t)j * 64, e2lns + (size_t)j * 64, e2lnb + (size_t)j * 64);
      float* tf = cur; cur = nxt; nxt = tf;
    }
    k_score<<<kB * kNEG, 128, 0, stream>>>(cur, q, batch, e2m1w, e2m1b, e2m2w, e2m2b, (float*)d_out);
  }
}

// Round 16
// 1064.394 us; speedup vs baseline: 1.2155x; 1.2155x over previous
//
#include <hip/hip_runtime.h>

constexpr int kB   = 4;
constexpr int kNEG = 33;
constexpr int kN   = 10000;
constexpr int kR   = 256;
constexpr int kD   = 64;
constexpr int kL   = 6;
constexpr int kE   = 200000;
constexpr int kER  = 80000;

typedef const float* fp;
typedef __attribute__((ext_vector_type(8))) short bf16x8;
typedef __attribute__((ext_vector_type(4))) float f32x4;

__device__ __forceinline__ float rdlane(float v, int l) {
  return __uint_as_float(__builtin_amdgcn_readlane(__float_as_uint(v), l));
}
__device__ __forceinline__ float wave_sum64(float v) {
  #pragma unroll
  for (int o = 32; o > 0; o >>= 1) v += __shfl_xor(v, o, 64);
  return v;
}
__device__ __forceinline__ float group_sum16(float v) {
  #pragma unroll
  for (int o = 8; o > 0; o >>= 1) v += __shfl_xor(v, o, 64);
  return v;
}
__device__ __forceinline__ short f2bf(float x) {
  unsigned u = __float_as_uint(x);
  unsigned r = (u + 0x7fffu + ((u >> 16) & 1u)) >> 16;
  return (short)r;
}
__device__ __forceinline__ float bf2f_u(unsigned short s) {
  return __uint_as_float(((unsigned)s) << 16);
}
__device__ __forceinline__ float bf2f(short s) { return bf2f_u((unsigned short)s); }

// ---------------- utility ----------------
__global__ void k_fill(float* __restrict__ p, float v, int n) {
  int i = blockIdx.x * blockDim.x + threadIdx.x;
  int stride = gridDim.x * blockDim.x;
  for (; i < n; i += stride) p[i] = v;
}
__global__ void k_zero_i(int* __restrict__ p, int n) {
  int i = blockIdx.x * blockDim.x + threadIdx.x;
  int stride = gridDim.x * blockDim.x;
  for (; i < n; i += stride) p[i] = 0;
}
__global__ void k_add_row(float* __restrict__ dst, const int* __restrict__ batch) {
  int tid = threadIdx.x;
  int b = tid >> 6, d = tid & 63;
  int row = batch[b * kNEG * 3 + 2];
  dst[((size_t)b * kR + row) * 64 + d] += 1.0f;
}
__global__ void k_add_row_ent(float* __restrict__ dst, const int* __restrict__ batch,
                              const float* __restrict__ q) {
  int tid = threadIdx.x;
  int b = tid >> 6, d = tid & 63;
  int row = batch[b * kNEG * 3];
  dst[((size_t)b * kN + row) * 64 + d] += q[b * 64 + d];
}
// also seed the bf16 [n][d][b] mirror with boundary values
__global__ void k_seed_mirror(const float* __restrict__ x, unsigned short* __restrict__ m) {
  int i = blockIdx.x * blockDim.x + threadIdx.x;  // over 2,560,000
  int stride = gridDim.x * blockDim.x;
  for (; i < kB * kN * kD; i += stride) {
    int d = i & 63, rem = i >> 6;
    int n = rem % kN, b = rem / kN;
    m[(size_t)n * 256 + d * 4 + b] = (unsigned short)f2bf(x[i]);
  }
}
__global__ void k_get_q(float* __restrict__ q, const float* __restrict__ relx,
                        const int* __restrict__ batch) {
  int tid = threadIdx.x;
  int b = tid >> 6, d = tid & 63;
  int r0 = batch[b * kNEG * 3 + 2];
  q[b * 64 + d] = relx[((size_t)b * kR + r0) * 64 + d];
}

// ---------------- CSR build ----------------
__global__ void k_hist(const int* __restrict__ dst, int ne, int* __restrict__ cnt) {
  int i = blockIdx.x * blockDim.x + threadIdx.x;
  if (i < ne) atomicAdd(&cnt[dst[i]], 1);
}
__global__ void k_fill_csr(const int* __restrict__ src, const int* __restrict__ dst,
                           const int* __restrict__ et, int ne,
                           int* __restrict__ cursor, int2* __restrict__ out) {
  int i = blockIdx.x * blockDim.x + threadIdx.x;
  if (i < ne) {
    int p = atomicAdd(&cursor[dst[i]], 1);
    out[p] = make_int2(src[i], et[i]);
  }
}
__global__ void k_hist_rel_lds(const int* __restrict__ rel_dst, int* __restrict__ cnt) {
  int g = blockIdx.y;
  __shared__ int lc[256];
  lc[threadIdx.x] = 0;
  __syncthreads();
  int lo = blockIdx.x * 8000, hi = min(lo + 8000, kER);
  for (int e = lo + threadIdx.x; e < hi; e += 256)
    atomicAdd(&lc[rel_dst[(size_t)g * kER + e]], 1);
  __syncthreads();
  int c = lc[threadIdx.x];
  if (c) atomicAdd(&cnt[g * 256 + threadIdx.x], c);
}
__global__ void k_fill_rel_lds(const int* __restrict__ src, const int* __restrict__ dst,
                               const int* __restrict__ et,
                               int* __restrict__ cursor, int2* __restrict__ out) {
  int g = blockIdx.y;
  __shared__ int lc[256];
  lc[threadIdx.x] = 0;
  __syncthreads();
  int lo = blockIdx.x * 8000, hi = min(lo + 8000, kER);
  const int* db = dst + (size_t)g * kER;
  for (int e = lo + threadIdx.x; e < hi; e += 256)
    atomicAdd(&lc[db[e]], 1);
  __syncthreads();
  int c = lc[threadIdx.x];
  __syncthreads();
  lc[threadIdx.x] = c ? atomicAdd(&cursor[g * 257 + threadIdx.x], c) : 0;
  __syncthreads();
  for (int e = lo + threadIdx.x; e < hi; e += 256) {
    int bin = db[e];
    int p = atomicAdd(&lc[bin], 1);
    out[(size_t)g * kER + p] = make_int2(src[(size_t)g * kER + e], et[(size_t)g * kER + e]);
  }
}
__global__ void k_scan_multi(const int* __restrict__ cnt, int* __restrict__ start,
                             int* __restrict__ cursor, int n, int cstride, int sstride) {
  const int* c = cnt + (size_t)blockIdx.x * cstride;
  int* st = start + (size_t)blockIdx.x * sstride;
  int* cu = cursor + (size_t)blockIdx.x * sstride;
  __shared__ int part[256];
  int t = threadIdx.x;
  int chunk = (n + 255) / 256;
  int lo = t * chunk, hi = min(lo + chunk, n);
  int s = 0;
  for (int i = lo; i < hi; ++i) s += c[i];
  part[t] = s;
  __syncthreads();
  if (t == 0) { int run = 0; for (int i = 0; i < 256; ++i) { int v = part[i]; part[i] = run; run += v; } }
  __syncthreads();
  int run = part[t];
  for (int i = lo; i < hi; ++i) { st[i] = run; cu[i] = run; run += c[i]; }
  if (t == 255) st[n] = run;
}

// ---------------- weight packing (MFMA B-frag order, bf16 hi/lo) ----------------
__global__ void k_packw(const float* __restrict__ w1, const float* __restrict__ w2,
                        short* __restrict__ w1h, short* __restrict__ w1l,
                        short* __restrict__ w2h, short* __restrict__ w2l) {
  int pg = blockIdx.x;
  for (int i = threadIdx.x; i < 4096; i += 256) {
    int t = i & 7, lane = (i >> 3) & 63, nt = (i >> 9) & 3, ks = i >> 11;
    int mr = lane & 15, kg = lane >> 4;
    int src = pg * 4096 + (ks * 32 + kg * 8 + t) * 64 + nt * 16 + mr;
    int dst = pg * 4096 + i;
    float v1 = w1[src]; short h1 = f2bf(v1);
    w1h[dst] = h1; w1l[dst] = f2bf(v1 - bf2f(h1));
    float v2 = w2[src]; short h2 = f2bf(v2);
    w2h[dst] = h2; w2l[dst] = f2bf(v2 - bf2f(h2));
  }
}
__global__ void k_packw_e(const float* __restrict__ w, short* __restrict__ wh, short* __restrict__ wl) {
  int set = blockIdx.x;
  for (int i = threadIdx.x; i < 8192; i += 256) {
    int t = i & 7, lane = (i >> 3) & 63, nt = (i >> 9) & 3, ks = i >> 11;
    int mr = lane & 15, kg = lane >> 4;
    int src = set * 8192 + (ks * 32 + kg * 8 + t) * 64 + nt * 16 + mr;
    int dst = set * 8192 + i;
    float v = w[src]; short h = f2bf(v);
    wh[dst] = h; wl[dst] = f2bf(v - bf2f(h));
  }
}

// ---------------- MFMA gate MLP (split-bf16), bf16 out in [g][n][d][b] ----------------
__global__ void __launch_bounds__(256) k_mlp_mfma(
    const float* __restrict__ in, const short* __restrict__ w1h, const short* __restrict__ w1l,
    const float* __restrict__ b1, const short* __restrict__ w2h, const short* __restrict__ w2l,
    const float* __restrict__ b2, int layer, unsigned short* __restrict__ out) {
  int g = blockIdx.y;
  int pg = g * kL + layer;
  int w = threadIdx.x >> 6, lane = threadIdx.x & 63;
  int mrow = lane & 15, kgrp = lane >> 4;
  int r0 = blockIdx.x * 64 + w * 16;
  __shared__ float hbuf[4][16][68];
  const float* xp = in + (size_t)(r0 + mrow) * 64 + kgrp * 8;
  bf16x8 a1h[2], a1l[2];
  #pragma unroll
  for (int ks = 0; ks < 2; ++ks) {
    #pragma unroll
    for (int t = 0; t < 8; ++t) {
      float v = xp[ks * 32 + t];
      short h = f2bf(v); a1h[ks][t] = h; a1l[ks][t] = f2bf(v - bf2f(h));
    }
  }
  const bf16x8* B1h = (const bf16x8*)(w1h + (size_t)pg * 4096);
  const bf16x8* B1l = (const bf16x8*)(w1l + (size_t)pg * 4096);
  #pragma unroll
  for (int nt = 0; nt < 4; ++nt) {
    f32x4 c = {0.f, 0.f, 0.f, 0.f};
    #pragma unroll
    for (int ks = 0; ks < 2; ++ks) {
      bf16x8 bh = B1h[(ks * 4 + nt) * 64 + lane];
      bf16x8 bl = B1l[(ks * 4 + nt) * 64 + lane];
      c = __builtin_amdgcn_mfma_f32_16x16x32_bf16(a1h[ks], bh, c, 0, 0, 0);
      c = __builtin_amdgcn_mfma_f32_16x16x32_bf16(a1h[ks], bl, c, 0, 0, 0);
      c = __builtin_amdgcn_mfma_f32_16x16x32_bf16(a1l[ks], bh, c, 0, 0, 0);
    }
    int col = nt * 16 + mrow;
    float bv = b1[pg * 64 + col];
    #pragma unroll
    for (int rg = 0; rg < 4; ++rg)
      hbuf[w][kgrp * 4 + rg][col] = fmaxf(c[rg] + bv, 0.f);
  }
  __syncthreads();
  bf16x8 a2h[2], a2l[2];
  #pragma unroll
  for (int ks = 0; ks < 2; ++ks) {
    #pragma unroll
    for (int t = 0; t < 8; ++t) {
      float v = hbuf[w][mrow][ks * 32 + kgrp * 8 + t];
      short h = f2bf(v); a2h[ks][t] = h; a2l[ks][t] = f2bf(v - bf2f(h));
    }
  }
  const bf16x8* B2h = (const bf16x8*)(w2h + (size_t)pg * 4096);
  const bf16x8* B2l = (const bf16x8*)(w2l + (size_t)pg * 4096);
  unsigned short* ob = out + (size_t)g * kB * kN * 64;
  #pragma unroll
  for (int nt = 0; nt < 4; ++nt) {
    f32x4 c = {0.f, 0.f, 0.f, 0.f};
    #pragma unroll
    for (int ks = 0; ks < 2; ++ks) {
      bf16x8 bh = B2h[(ks * 4 + nt) * 64 + lane];
      bf16x8 bl = B2l[(ks * 4 + nt) * 64 + lane];
      c = __builtin_amdgcn_mfma_f32_16x16x32_bf16(a2h[ks], bh, c, 0, 0, 0);
      c = __builtin_amdgcn_mfma_f32_16x16x32_bf16(a2h[ks], bl, c, 0, 0, 0);
      c = __builtin_amdgcn_mfma_f32_16x16x32_bf16(a2l[ks], bh, c, 0, 0, 0);
    }
    int col = nt * 16 + mrow;
    float bv = b2[pg * 64 + col];
    #pragma unroll
    for (int rg = 0; rg < 4; ++rg) {
      int grow = r0 + kgrp * 4 + rg;          // = b*kN + n
      int bb = grow / kN;
      int nn = grow - bb * kN;
      ob[(size_t)nn * 256 + col * 4 + bb] = (unsigned short)f2bf(c[rg] + bv);  // [n][d][b]
    }
  }
}

// ---------------- rel-gate MLP for entity phase: bf16 out in [j][r][d][b] ----------------
__global__ void __launch_bounds__(256) k_mlp_rel6(
    const float* __restrict__ in, fp p1w, fp p1b, fp p2w, fp p2b,
    unsigned short* __restrict__ out) {
  int j = blockIdx.y;
  int row = blockIdx.x * 4 + (threadIdx.x >> 6);   // = b*256 + r
  int lane = threadIdx.x & 63;
  fp W1 = p1w + (size_t)j * 4096;
  fp W2 = p2w + (size_t)j * 4096;
  float xv = in[(size_t)row * 64 + lane];
  float a = p1b[j * 64 + lane];
  float wbuf[8];
  #pragma unroll
  for (int kk = 0; kk < 64; kk += 8) {
    #pragma unroll
    for (int u = 0; u < 8; ++u) wbuf[u] = W1[(kk + u) * 64 + lane];
    #pragma unroll
    for (int u = 0; u < 8; ++u) a = fmaf(rdlane(xv, kk + u), wbuf[u], a);
  }
  a = fmaxf(a, 0.f);
  float c = p2b[j * 64 + lane];
  #pragma unroll
  for (int kk = 0; kk < 64; kk += 8) {
    #pragma unroll
    for (int u = 0; u < 8; ++u) wbuf[u] = W2[(kk + u) * 64 + lane];
    #pragma unroll
    for (int u = 0; u < 8; ++u) c = fmaf(rdlane(a, kk + u), wbuf[u], c);
  }
  int b = row >> 8, r = row & 255;
  out[((size_t)j * kR + r) * 256 + lane * 4 + b] = (unsigned short)f2bf(c);  // [r][d][b]
}

// ---------------- i=0 rel specials ----------------
__global__ void k_gate0(fp p1w, fp p1b, fp p2w, fp p2b, float* __restrict__ gate0) {
  int g = threadIdx.x >> 6, lane = threadIdx.x & 63;
  int pg = g * kL;
  float a = p1b[pg * 64 + lane];
  #pragma unroll
  for (int k = 0; k < 64; ++k) a += p1w[(size_t)pg * 4096 + k * 64 + lane];
  a = fmaxf(a, 0.f);
  float c = p2b[pg * 64 + lane];
  #pragma unroll
  for (int k = 0; k < 64; ++k)
    c = fmaf(rdlane(a, k), p2w[(size_t)pg * 4096 + k * 64 + lane], c);
  gate0[g * 64 + lane] = c;
}
__global__ void k_rel_agg0(const int* __restrict__ rel_start, const int2* __restrict__ rel_edges,
                           const int* __restrict__ batch, const float* __restrict__ gate0,
                           float* __restrict__ agg) {
  int wid = (blockIdx.x * blockDim.x + threadIdx.x) >> 6;
  int lane = threadIdx.x & 63;
  int g = wid >> 10, rem = wid & 1023, b = rem >> 8, r = rem & 255;
  int r0 = batch[b * kNEG * 3 + 2];
  const int* start = rel_start + g * 257;
  const int2* edges = rel_edges + (size_t)g * kER;
  int s0 = start[r], s1 = start[r + 1];
  int cnt = 0;
  for (int base = s0; base < s1; base += 64) {
    int e = base + lane;
    bool m = false;
    if (e < s1) m = (edges[e].x == r0);
    cnt += (int)__popcll(__ballot(m));
  }
  agg[(size_t)wid * 64 + lane] = gate0[g * 64 + lane] * (float)cnt + ((r == r0) ? 1.f : 0.f);
}

// ---------------- rel gather: block=(g,r), d-major, 2-deep payload pipeline ----------------
__global__ void __launch_bounds__(256) k_gather_rel_all(
    const float* __restrict__ rxi, const unsigned short* __restrict__ gateN,
    const int* __restrict__ rel_start, const int2* __restrict__ rel_edges,
    const int* __restrict__ batch, float* __restrict__ agg) {
  int i = blockIdx.x;                  // 1024 = r*4 + g
  int g = i & 3, r = i >> 2;
  const unsigned short* gate = gateN + (size_t)g * kB * kN * 64;
  const int* start = rel_start + g * 257;
  const int2* edges = rel_edges + (size_t)g * kER;
  int w = threadIdx.x >> 6, lane = threadIdx.x & 63;
  int s0 = start[r], s1 = start[r + 1];
  int len = s1 - s0;
  int per = (len + 3) >> 2;
  int e0 = s0 + w * per, e1 = min(e0 + per, s1);
  float a0 = 0.f, a1 = 0.f, a2 = 0.f, a3 = 0.f;
  if (e0 < e1) {
    int last = e1 - 1;
    int2 i0 = edges[e0];
    int2 i1 = edges[min(e0 + 1, last)];
    float4 xv0 = *((const float4*)(rxi + (size_t)i0.x * 256) + lane);
    ushort4 gv0 = *((const ushort4*)(gate + (size_t)i0.y * 256) + lane);
    for (int e = e0; e < e1; ++e) {
      int2 i2 = edges[min(e + 2, last)];
      float4 xv1 = *((const float4*)(rxi + (size_t)i1.x * 256) + lane);
      ushort4 gv1 = *((const ushort4*)(gate + (size_t)i1.y * 256) + lane);
      a0 = fmaf(xv0.x, bf2f_u(gv0.x), a0);
      a1 = fmaf(xv0.y, bf2f_u(gv0.y), a1);
      a2 = fmaf(xv0.z, bf2f_u(gv0.z), a2);
      a3 = fmaf(xv0.w, bf2f_u(gv0.w), a3);
      i1 = i2; xv0 = xv1; gv0 = gv1;
    }
  }
  __shared__ float red[4][4][64];
  red[w][0][lane] = a0; red[w][1][lane] = a1; red[w][2][lane] = a2; red[w][3][lane] = a3;
  __syncthreads();
  float a = red[0][w][lane] + red[1][w][lane] + red[2][w][lane] + red[3][w][lane];
  int r0b = batch[w * kNEG * 3 + 2];
  if (r == r0b) a += 1.0f;
  agg[(((size_t)g * kB + w) * kR + r) * 64 + lane] = a;
}

// ---------------- rel conv partial: grid (64, g) ----------------
__global__ void __launch_bounds__(256) k_conv_rel3(
    const float* __restrict__ rel_x, float* __restrict__ agg,
    fp rlw, fp rlb, fp rlns, fp rlnb, int layer) {
  int g = blockIdx.y;
  int pg = g * kL + layer;
  int wave = threadIdx.x >> 6, lane = threadIdx.x & 63;
  int row0 = blockIdx.x * 16 + wave * 4;
  const float* xp = rel_x + (size_t)row0 * 64 + lane;
  float* ap = agg + ((size_t)g * 1024 + row0) * 64 + lane;
  float x0 = xp[0], x1 = xp[64], x2 = xp[128], x3 = xp[192];
  float g0 = ap[0], g1 = ap[64], g2 = ap[128], g3 = ap[192];
  fp w1 = rlw + (size_t)pg * 8192;
  float bv = rlb[pg * 64 + lane];
  float o0 = bv, o1 = bv, o2 = bv, o3 = bv;
  float wbuf[8];
  #pragma unroll
  for (int kk = 0; kk < 128; kk += 8) {
    #pragma unroll
    for (int u = 0; u < 8; ++u) wbuf[u] = w1[(kk + u) * 64 + lane];
    #pragma unroll
    for (int u = 0; u < 8; ++u) {
      int k = kk + u; float w = wbuf[u];
      if (k < 64) {
        o0 = fmaf(rdlane(x0, k), w, o0); o1 = fmaf(rdlane(x1, k), w, o1);
        o2 = fmaf(rdlane(x2, k), w, o2); o3 = fmaf(rdlane(x3, k), w, o3);
      } else {
        o0 = fmaf(rdlane(g0, k - 64), w, o0); o1 = fmaf(rdlane(g1, k - 64), w, o1);
        o2 = fmaf(rdlane(g2, k - 64), w, o2); o3 = fmaf(rdlane(g3, k - 64), w, o3);
      }
    }
  }
  float s = rlns[pg * 64 + lane], t = rlnb[pg * 64 + lane];
  { float m = wave_sum64(o0) * (1.f/64.f); float c = o0 - m;
    float v = wave_sum64(c*c) * (1.f/64.f);
    ap[0] = fmaxf(c * rsqrtf(v + 1e-5f) * s + t, 0.f); }
  { float m = wave_sum64(o1) * (1.f/64.f); float c = o1 - m;
    float v = wave_sum64(c*c) * (1.f/64.f);
    ap[64] = fmaxf(c * rsqrtf(v + 1e-5f) * s + t, 0.f); }
  { float m = wave_sum64(o2) * (1.f/64.f); float c = o2 - m;
    float v = wave_sum64(c*c) * (1.f/64.f);
    ap[128] = fmaxf(c * rsqrtf(v + 1e-5f) * s + t, 0.f); }
  { float m = wave_sum64(o3) * (1.f/64.f); float c = o3 - m;
    float v = wave_sum64(c*c) * (1.f/64.f);
    ap[192] = fmaxf(c * rsqrtf(v + 1e-5f) * s + t, 0.f); }
}

// rel_x += sum_g y[g]; maintain d-major mirror rxi[r][d][b]
__global__ void k_sum_rel(float* __restrict__ rel_x, float* __restrict__ rxi,
                          const float* __restrict__ y) {
  int i = blockIdx.x * blockDim.x + threadIdx.x;   // 65536
  float v = rel_x[i] + y[i] + y[65536 + i] + y[131072 + i] + y[196608 + i];
  rel_x[i] = v;
  int d = i & 63, row = i >> 6;
  int b = row >> 8, r = row & 255;
  rxi[(size_t)r * 256 + d * 4 + b] = v;
}

// ---------------- ent gather: wave = node, 4 batches, 2-deep payload pipeline ----------------
template<bool FIRST>
__global__ void __launch_bounds__(256) k_ent_gather(
    const unsigned short* __restrict__ xbf_cur, const unsigned short* __restrict__ gateL,
    const int* __restrict__ start, const int2* __restrict__ edges,
    const float* __restrict__ q, const int* __restrict__ batch,
    float* __restrict__ agg) {
  int n = (blockIdx.x * blockDim.x + threadIdx.x) >> 6;
  if (n >= kN) return;
  int lane = threadIdx.x & 63;
  int h0[4]; float qv[4];
  #pragma unroll
  for (int b = 0; b < 4; ++b) { h0[b] = batch[b * kNEG * 3]; qv[b] = q[b * 64 + lane]; }
  float a0 = 0.f, a1 = 0.f, a2 = 0.f, a3 = 0.f;
  int s0 = start[n], s1 = start[n + 1];
  if (s0 < s1) {
    int last = s1 - 1;
    int2 i0 = edges[s0];
    int2 i1 = edges[min(s0 + 1, last)];
    ushort4 gv0 = *((const ushort4*)(gateL + (size_t)i0.y * 256) + lane);
    ushort4 xv0;
    if (!FIRST) xv0 = *((const ushort4*)(xbf_cur + (size_t)i0.x * 256) + lane);
    for (int e = s0; e < s1; ++e) {
      int2 i2 = edges[min(e + 2, last)];
      ushort4 gv1 = *((const ushort4*)(gateL + (size_t)i1.y * 256) + lane);
      ushort4 xv1;
      if (!FIRST) xv1 = *((const ushort4*)(xbf_cur + (size_t)i1.x * 256) + lane);
      if (FIRST) {
        if (i0.x == h0[0]) a0 = fmaf(qv[0], bf2f_u(gv0.x), a0);
        if (i0.x == h0[1]) a1 = fmaf(qv[1], bf2f_u(gv0.y), a1);
        if (i0.x == h0[2]) a2 = fmaf(qv[2], bf2f_u(gv0.z), a2);
        if (i0.x == h0[3]) a3 = fmaf(qv[3], bf2f_u(gv0.w), a3);
      } else {
        a0 = fmaf(bf2f_u(xv0.x), bf2f_u(gv0.x), a0);
        a1 = fmaf(bf2f_u(xv0.y), bf2f_u(gv0.y), a1);
        a2 = fmaf(bf2f_u(xv0.z), bf2f_u(gv0.z), a2);
        a3 = fmaf(bf2f_u(xv0.w), bf2f_u(gv0.w), a3);
      }
      i0 = i1; i1 = i2; gv0 = gv1;
      if (!FIRST) xv0 = xv1;
    }
  }
  if (n == h0[0]) a0 += qv[0];
  if (n == h0[1]) a1 += qv[1];
  if (n == h0[2]) a2 += qv[2];
  if (n == h0[3]) a3 += qv[3];
  float* ap = agg + (size_t)n * 64 + lane;
  ap[0] = a0; ap[640000] = a1; ap[1280000] = a2; ap[1920000] = a3;
}

// ---------------- ent conv via MFMA: y = x + relu(LN(concat(x,agg)@lw + lb)) ----------------
__global__ void __launch_bounds__(256) k_ent_conv_mfma(
    const float* __restrict__ xcur, const float* __restrict__ aggv,
    float* __restrict__ xnext, unsigned short* __restrict__ xbf_next,
    const short* __restrict__ wh, const short* __restrict__ wl, int set,
    fp lb, fp lns, fp lnb) {
  int w = threadIdx.x >> 6, lane = threadIdx.x & 63;
  int mrow = lane & 15, kgrp = lane >> 4;
  int r0 = blockIdx.x * 64 + w * 16;
  int arow = r0 + mrow;
  bf16x8 ah[4], al[4];
  #pragma unroll
  for (int ks = 0; ks < 4; ++ks) {
    const float* p = (ks < 2) ? (xcur + (size_t)arow * 64 + ks * 32 + kgrp * 8)
                              : (aggv + (size_t)arow * 64 + (ks - 2) * 32 + kgrp * 8);
    #pragma unroll
    for (int t = 0; t < 8; ++t) {
      float v = p[t];
      short h = f2bf(v); ah[ks][t] = h; al[ks][t] = f2bf(v - bf2f(h));
    }
  }
  const bf16x8* Bh = (const bf16x8*)(wh + (size_t)set * 8192);
  const bf16x8* Bl = (const bf16x8*)(wl + (size_t)set * 8192);
  float o[4][4];
  #pragma unroll
  for (int nt = 0; nt < 4; ++nt) {
    f32x4 c = {0.f, 0.f, 0.f, 0.f};
    #pragma unroll
    for (int ks = 0; ks < 4; ++ks) {
      bf16x8 bh = Bh[(ks * 4 + nt) * 64 + lane];
      bf16x8 bl = Bl[(ks * 4 + nt) * 64 + lane];
      c = __builtin_amdgcn_mfma_f32_16x16x32_bf16(ah[ks], bh, c, 0, 0, 0);
      c = __builtin_amdgcn_mfma_f32_16x16x32_bf16(ah[ks], bl, c, 0, 0, 0);
      c = __builtin_amdgcn_mfma_f32_16x16x32_bf16(al[ks], bh, c, 0, 0, 0);
    }
    float bv = lb[nt * 16 + mrow];
    #pragma unroll
    for (int rg = 0; rg < 4; ++rg) o[nt][rg] = c[rg] + bv;
  }
  float mean[4], varr[4];
  #pragma unroll
  for (int rg = 0; rg < 4; ++rg) {
    float p = o[0][rg] + o[1][rg] + o[2][rg] + o[3][rg];
    mean[rg] = group_sum16(p) * (1.f / 64.f);
    float d0 = o[0][rg] - mean[rg], d1 = o[1][rg] - mean[rg];
    float d2 = o[2][rg] - mean[rg], d3 = o[3][rg] - mean[rg];
    float vs = d0 * d0 + d1 * d1 + d2 * d2 + d3 * d3;
    varr[rg] = group_sum16(vs) * (1.f / 64.f);
  }
  #pragma unroll
  for (int nt = 0; nt < 4; ++nt) {
    int col = nt * 16 + mrow;
    float s = lns[col], tt = lnb[col];
    #pragma unroll
    for (int rg = 0; rg < 4; ++rg) {
      int grow = r0 + kgrp * 4 + rg;
      float xv = xcur[(size_t)grow * 64 + col];
      float y = xv + fmaxf((o[nt][rg] - mean[rg]) * rsqrtf(varr[rg] + 1e-5f) * s + tt, 0.f);
      xnext[(size_t)grow * 64 + col] = y;
      int bb = grow / kN;
      int nn = grow - bb * kN;
      xbf_next[(size_t)nn * 256 + col * 4 + bb] = (unsigned short)f2bf(y);
    }
  }
}

// ---------------- node_reps = concat(ent_x, q)@nmw + nmb ----------------
__global__ void __launch_bounds__(256) k_nodeup4(
    const float* __restrict__ x, const float* __restrict__ q,
    fp nmw, fp nmb, float* __restrict__ out) {
  int wid = (blockIdx.x * blockDim.x + threadIdx.x) >> 6;
  int lane = threadIdx.x & 63;
  int r0 = wid * 4;
  if (r0 >= kB * kN) return;
  int b = r0 / kN;
  const float* ip = x + (size_t)r0 * 64 + lane;
  float x0 = ip[0], x1 = ip[64], x2 = ip[128], x3 = ip[192];
  float qv = q[b * 64 + lane];
  float bv = nmb[lane];
  float c0 = bv, c1 = bv, c2 = bv, c3 = bv;
  float wbuf[4];
  #pragma unroll
  for (int kk = 0; kk < 64; kk += 4) {
    #pragma unroll
    for (int u = 0; u < 4; ++u) wbuf[u] = nmw[(kk + u) * 64 + lane];
    #pragma unroll
    for (int u = 0; u < 4; ++u) {
      int k = kk + u; float w = wbuf[u];
      c0 = fmaf(rdlane(x0, k), w, c0); c1 = fmaf(rdlane(x1, k), w, c1);
      c2 = fmaf(rdlane(x2, k), w, c2); c3 = fmaf(rdlane(x3, k), w, c3);
    }
  }
  float qa = 0.f;
  #pragma unroll
  for (int k = 0; k < 64; ++k)
    qa = fmaf(rdlane(qv, k), nmw[(64 + k) * 64 + lane], qa);
  float* op = out + (size_t)r0 * 64 + lane;
  op[0] = c0 + qa; op[64] = c1 + qa; op[128] = c2 + qa; op[192] = c3 + qa;
}

// ---------------- final scoring ----------------
__global__ void k_score(const float* __restrict__ entx, const float* __restrict__ q,
                        const int* __restrict__ batch,
                        fp m1w, fp m1b, fp m2w, fp m2b,
                        float* __restrict__ out) {
  int b = blockIdx.x / kNEG, n = blockIdx.x % kNEG;
  int t = batch[(b * kNEG + n) * 3 + 1];
  int j = threadIdx.x;
  __shared__ float gv[128];
  __shared__ float red[2];
  gv[j] = (j < 64) ? entx[((size_t)b * kN + t) * 64 + j] : q[b * 64 + (j - 64)];
  __syncthreads();
  float acc = m1b[j];
  #pragma unroll 16
  for (int k = 0; k < 128; ++k)
    acc = fmaf(gv[k], m1w[k * 128 + j], acc);
  float h = fmaxf(acc, 0.f) * m2w[j];
  h = wave_sum64(h);
  if ((j & 63) == 0) red[j >> 6] = h;
  __syncthreads();
  if (j == 0) out[b * kNEG + n] = red[0] + red[1] + m2b[0];
}

// ---------------- host ----------------
extern "C" void kernel_launch(void* const* d_in, const int* in_sizes, int n_in,
                              void* d_out, int out_size, void* d_ws, size_t ws_size,
                              hipStream_t stream) {
  const int* edge_src  = (const int*)d_in[0];
  const int* edge_dst  = (const int*)d_in[1];
  const int* edge_type = (const int*)d_in[2];
  const int* rel_src   = (const int*)d_in[3];
  const int* rel_dst   = (const int*)d_in[4];
  const int* rel_etype = (const int*)d_in[5];
  const int* batch     = (const int*)d_in[6];
  fp e1p1w = (fp)d_in[7],  e1p1b = (fp)d_in[8],  e1p2w = (fp)d_in[9],  e1p2b = (fp)d_in[10];
  fp e1lw  = (fp)d_in[11], e1lb  = (fp)d_in[12], e1lns = (fp)d_in[13], e1lnb = (fp)d_in[14];
  fp e2p1w = (fp)d_in[15], e2p1b = (fp)d_in[16], e2p2w = (fp)d_in[17], e2p2b = (fp)d_in[18];
  fp e2lw  = (fp)d_in[19], e2lb  = (fp)d_in[20], e2lns = (fp)d_in[21], e2lnb = (fp)d_in[22];
  fp e2m1w = (fp)d_in[23], e2m1b = (fp)d_in[24], e2m2w = (fp)d_in[25], e2m2b = (fp)d_in[26];
  fp rp1w  = (fp)d_in[27], rp1b  = (fp)d_in[28], rp2w  = (fp)d_in[29], rp2b  = (fp)d_in[30];
  fp rlw   = (fp)d_in[31], rlb   = (fp)d_in[32], rlns  = (fp)d_in[33], rlnb  = (fp)d_in[34];
  fp nmw   = (fp)d_in[35], nmb   = (fp)d_in[36];

  float* ws = (float*)d_ws;
  float* rel_x     = ws;                           // 65,536
  float* q         = rel_x + 65536;                // 256
  float* gate0     = q + 256;                      // 256
  float* rxi       = gate0 + 256;                  // 65,536 ([r][d][b])
  float* rel_agg   = rxi + 65536;                  // 262,144
  float* node_reps = rel_agg + 262144;             // 2,560,000
  float* ent_xa    = node_reps + 2560000;          // 2,560,000
  float* ent_xb    = ent_xa + 2560000;             // 2,560,000
  float* ent_agg   = ent_xb + 2560000;             // 2,560,000 ([b][n][d])
  unsigned short* gateR6 = (unsigned short*)(ent_agg + 2560000); // 393,216 ([j][r][d][b])
  unsigned short* gateN  = gateR6 + 393216;        // 10,240,000 ([g][n][d][b])
  unsigned short* ent_ba = gateN + 10240000;       // 2,560,000 ([n][d][b])
  unsigned short* ent_bb = ent_ba + 2560000;       // 2,560,000
  int*   iws       = (int*)(ent_bb + 2560000);
  int2*  ent_edges = (int2*)iws;                   // 400,000 ints
  int2*  rel_edges = (int2*)(iws + 400000);        // 640,000 ints
  int*   ent_cnt   = iws + 400000 + 640000;        // 10,000
  int*   ent_start = ent_cnt + 10000;              // 10,001
  int*   ent_cur   = ent_start + 10001;            // 10,001
  int*   rel_cnt   = ent_cur + 10001;              // 1,024
  int*   rel_start = rel_cnt + 1024;               // 1,028
  int*   rel_cur   = rel_start + 1028;             // 1,028
  short* w1hp      = (short*)(rel_cur + 1028 + 2); // 98,304 shorts each
  short* w1lp      = w1hp + 98304;
  short* w2hp      = w1lp + 98304;
  short* w2lp      = w2hp + 98304;
  short* elwh      = w2lp + 98304;                 // 12*8192
  short* elwl      = elwh + 98304;

  const int nZero = 10000 + 10001 + 10001 + 1024;
  // ---- CSR build + weight packing ----
  k_zero_i<<<(nZero + 255) / 256, 256, 0, stream>>>(ent_cnt, nZero);
  k_hist<<<(kE + 255) / 256, 256, 0, stream>>>(edge_dst, kE, ent_cnt);
  k_hist_rel_lds<<<dim3(10, 4), 256, 0, stream>>>(rel_dst, rel_cnt);
  k_scan_multi<<<1, 256, 0, stream>>>(ent_cnt, ent_start, ent_cur, 10000, 0, 0);
  k_scan_multi<<<4, 256, 0, stream>>>(rel_cnt, rel_start, rel_cur, 256, 256, 257);
  k_fill_csr<<<(kE + 255) / 256, 256, 0, stream>>>(edge_src, edge_dst, edge_type, kE, ent_cur, ent_edges);
  k_fill_rel_lds<<<dim3(10, 4), 256, 0, stream>>>(rel_src, rel_dst, rel_etype, rel_cur, rel_edges);
  k_packw<<<24, 256, 0, stream>>>(rp1w, rp2w, w1hp, w1lp, w2hp, w2lp);
  k_packw_e<<<6, 256, 0, stream>>>(e1lw, elwh, elwl);
  k_packw_e<<<6, 256, 0, stream>>>(e2lw, elwh + 6 * 8192, elwl + 6 * 8192);

  // ---- rel_x = one-hot boundary ----
  k_fill<<<256, 256, 0, stream>>>(rel_x, 0.f, kB * kR * kD);
  k_add_row<<<1, 256, 0, stream>>>(rel_x, batch);

  // ---- i = 0 (node_reps == ones) ----
  k_gate0<<<1, 256, 0, stream>>>(rp1w, rp1b, rp2w, rp2b, gate0);
  k_rel_agg0<<<1024, 256, 0, stream>>>(rel_start, rel_edges, batch, gate0, rel_agg);
  k_conv_rel3<<<dim3(64, 4), 256, 0, stream>>>(rel_x, rel_agg, rlw, rlb, rlns, rlnb, 0);
  k_sum_rel<<<256, 256, 0, stream>>>(rel_x, rxi, rel_agg);

  // ---- entity_bf with e1 params -> node_reps ----
  k_get_q<<<1, 256, 0, stream>>>(q, rel_x, batch);
  k_mlp_rel6<<<dim3(256, 6), 256, 0, stream>>>(rel_x, e1p1w, e1p1b, e1p2w, e1p2b, gateR6);
  k_fill<<<2048, 256, 0, stream>>>(ent_xa, 0.f, kB * kN * kD);
  k_add_row_ent<<<1, 256, 0, stream>>>(ent_xa, batch, q);
  {
    float* cur = ent_xa; float* nxt = ent_xb;
    unsigned short* bcur = ent_ba; unsigned short* bnxt = ent_bb;
    for (int j = 0; j < kL; ++j) {
      const unsigned short* gL = gateR6 + (size_t)j * kR * 256;
      if (j == 0)
        k_ent_gather<true><<<2500, 256, 0, stream>>>(bcur, gL, ent_start, ent_edges, q, batch, ent_agg);
      else
        k_ent_gather<false><<<2500, 256, 0, stream>>>(bcur, gL, ent_start, ent_edges, q, batch, ent_agg);
      k_ent_conv_mfma<<<625, 256, 0, stream>>>(cur, ent_agg, nxt, bnxt, elwh, elwl, j,
          e1lb + (size_t)j * 64, e1lns + (size_t)j * 64, e1lnb + (size_t)j * 64);
      float* tf = cur; cur = nxt; nxt = tf;
      unsigned short* tb = bcur; bcur = bnxt; bnxt = tb;
    }
    k_nodeup4<<<2500, 256, 0, stream>>>(cur, q, nmw, nmb, node_reps);
  }

  // ---- i = 1..5 ----
  for (int i = 1; i < kL; ++i) {
    k_mlp_mfma<<<dim3(625, 4), 256, 0, stream>>>(node_reps, w1hp, w1lp, rp1b, w2hp, w2lp, rp2b, i, gateN);
    k_gather_rel_all<<<1024, 256, 0, stream>>>(rxi, gateN, rel_start, rel_edges, batch, rel_agg);
    k_conv_rel3<<<dim3(64, 4), 256, 0, stream>>>(rel_x, rel_agg, rlw, rlb, rlns, rlnb, i);
    k_sum_rel<<<256, 256, 0, stream>>>(rel_x, rxi, rel_agg);
  }

  // ---- entity_bf with e2 params + scoring ----
  k_get_q<<<1, 256, 0, stream>>>(q, rel_x, batch);
  k_mlp_rel6<<<dim3(256, 6), 256, 0, stream>>>(rel_x, e2p1w, e2p1b, e2p2w, e2p2b, gateR6);
  k_fill<<<2048, 256, 0, stream>>>(ent_xa, 0.f, kB * kN * kD);
  k_add_row_ent<<<1, 256, 0, stream>>>(ent_xa, batch, q);
  {
    float* cur = ent_xa; float* nxt = ent_xb;
    unsigned short* bcur = ent_ba; unsigned short* bnxt = ent_bb;
    for (int j = 0; j < kL; ++j) {
      const unsigned short* gL = gateR6 + (size_t)j * kR * 256;
      if (j == 0)
        k_ent_gather<true><<<2500, 256, 0, stream>>>(bcur, gL, ent_start, ent_edges, q, batch, ent_agg);
      else
        k_ent_gather<false><<<2500, 256, 0, stream>>>(bcur, gL, ent_start, ent_edges, q, batch, ent_agg);
      k_ent_conv_mfma<<<625, 256, 0, stream>>>(cur, ent_agg, nxt, bnxt, elwh, elwl, 6 + j,
          e2lb + (size_t)j * 64, e2lns + (size_t)j * 64, e2lnb + (size_t)j * 64);
      float* tf = cur; cur = nxt; nxt = tf;
      unsigned short* tb = bcur; bcur = bnxt; bnxt = tb;
    }
    k_score<<<kB * kNEG, 128, 0, stream>>>(cur, q, batch, e2m1w, e2m1b, e2m2w, e2m2b, (float*)d_out);
  }
}

// Round 17
// 1001.355 us; speedup vs baseline: 1.2920x; 1.0630x over previous
//
#include <hip/hip_runtime.h>

constexpr int kB   = 4;
constexpr int kNEG = 33;
constexpr int kN   = 10000;
constexpr int kR   = 256;
constexpr int kD   = 64;
constexpr int kL   = 6;
constexpr int kE   = 200000;
constexpr int kER  = 80000;

typedef const float* fp;
typedef __attribute__((ext_vector_type(8))) short bf16x8;
typedef __attribute__((ext_vector_type(4))) float f32x4;

__device__ __forceinline__ float rdlane(float v, int l) {
  return __uint_as_float(__builtin_amdgcn_readlane(__float_as_uint(v), l));
}
__device__ __forceinline__ float wave_sum64(float v) {
  #pragma unroll
  for (int o = 32; o > 0; o >>= 1) v += __shfl_xor(v, o, 64);
  return v;
}
__device__ __forceinline__ float group_sum16(float v) {
  #pragma unroll
  for (int o = 8; o > 0; o >>= 1) v += __shfl_xor(v, o, 64);
  return v;
}
__device__ __forceinline__ short f2bf(float x) {
  unsigned u = __float_as_uint(x);
  unsigned r = (u + 0x7fffu + ((u >> 16) & 1u)) >> 16;
  return (short)r;
}
__device__ __forceinline__ float bf2f_u(unsigned short s) {
  return __uint_as_float(((unsigned)s) << 16);
}
__device__ __forceinline__ float bf2f(short s) { return bf2f_u((unsigned short)s); }

// ---------------- utility ----------------
__global__ void k_fill(float* __restrict__ p, float v, int n) {
  int i = blockIdx.x * blockDim.x + threadIdx.x;
  int stride = gridDim.x * blockDim.x;
  for (; i < n; i += stride) p[i] = v;
}
__global__ void k_zero_i(int* __restrict__ p, int n) {
  int i = blockIdx.x * blockDim.x + threadIdx.x;
  int stride = gridDim.x * blockDim.x;
  for (; i < n; i += stride) p[i] = 0;
}
__global__ void k_add_row(float* __restrict__ dst, const int* __restrict__ batch) {
  int tid = threadIdx.x;
  int b = tid >> 6, d = tid & 63;
  int row = batch[b * kNEG * 3 + 2];
  dst[((size_t)b * kR + row) * 64 + d] += 1.0f;
}
__global__ void k_add_row_ent(float* __restrict__ dst, const int* __restrict__ batch,
                              const float* __restrict__ q) {
  int tid = threadIdx.x;
  int b = tid >> 6, d = tid & 63;
  int row = batch[b * kNEG * 3];
  dst[((size_t)b * kN + row) * 64 + d] += q[b * 64 + d];
}
__global__ void k_get_q(float* __restrict__ q, const float* __restrict__ relx,
                        const int* __restrict__ batch) {
  int tid = threadIdx.x;
  int b = tid >> 6, d = tid & 63;
  int r0 = batch[b * kNEG * 3 + 2];
  q[b * 64 + d] = relx[((size_t)b * kR + r0) * 64 + d];
}

// ---------------- CSR build ----------------
__global__ void k_hist(const int* __restrict__ dst, int ne, int* __restrict__ cnt) {
  int i = blockIdx.x * blockDim.x + threadIdx.x;
  if (i < ne) atomicAdd(&cnt[dst[i]], 1);
}
__global__ void k_fill_csr(const int* __restrict__ src, const int* __restrict__ dst,
                           const int* __restrict__ et, int ne,
                           int* __restrict__ cursor, int2* __restrict__ out) {
  int i = blockIdx.x * blockDim.x + threadIdx.x;
  if (i < ne) {
    int p = atomicAdd(&cursor[dst[i]], 1);
    out[p] = make_int2(src[i], et[i]);
  }
}
__global__ void k_hist_rel_lds(const int* __restrict__ rel_dst, int* __restrict__ cnt) {
  int g = blockIdx.y;
  __shared__ int lc[256];
  lc[threadIdx.x] = 0;
  __syncthreads();
  int lo = blockIdx.x * 8000, hi = min(lo + 8000, kER);
  for (int e = lo + threadIdx.x; e < hi; e += 256)
    atomicAdd(&lc[rel_dst[(size_t)g * kER + e]], 1);
  __syncthreads();
  int c = lc[threadIdx.x];
  if (c) atomicAdd(&cnt[g * 256 + threadIdx.x], c);
}
__global__ void k_fill_rel_lds(const int* __restrict__ src, const int* __restrict__ dst,
                               const int* __restrict__ et,
                               int* __restrict__ cursor, int2* __restrict__ out) {
  int g = blockIdx.y;
  __shared__ int lc[256];
  lc[threadIdx.x] = 0;
  __syncthreads();
  int lo = blockIdx.x * 8000, hi = min(lo + 8000, kER);
  const int* db = dst + (size_t)g * kER;
  for (int e = lo + threadIdx.x; e < hi; e += 256)
    atomicAdd(&lc[db[e]], 1);
  __syncthreads();
  int c = lc[threadIdx.x];
  __syncthreads();
  lc[threadIdx.x] = c ? atomicAdd(&cursor[g * 257 + threadIdx.x], c) : 0;
  __syncthreads();
  for (int e = lo + threadIdx.x; e < hi; e += 256) {
    int bin = db[e];
    int p = atomicAdd(&lc[bin], 1);
    out[(size_t)g * kER + p] = make_int2(src[(size_t)g * kER + e], et[(size_t)g * kER + e]);
  }
}
__global__ void k_scan_multi(const int* __restrict__ cnt, int* __restrict__ start,
                             int* __restrict__ cursor, int n, int cstride, int sstride) {
  const int* c = cnt + (size_t)blockIdx.x * cstride;
  int* st = start + (size_t)blockIdx.x * sstride;
  int* cu = cursor + (size_t)blockIdx.x * sstride;
  __shared__ int part[256];
  int t = threadIdx.x;
  int chunk = (n + 255) / 256;
  int lo = t * chunk, hi = min(lo + chunk, n);
  int s = 0;
  for (int i = lo; i < hi; ++i) s += c[i];
  part[t] = s;
  __syncthreads();
  if (t == 0) { int run = 0; for (int i = 0; i < 256; ++i) { int v = part[i]; part[i] = run; run += v; } }
  __syncthreads();
  int run = part[t];
  for (int i = lo; i < hi; ++i) { st[i] = run; cu[i] = run; run += c[i]; }
  if (t == 255) st[n] = run;
}

// ---------------- weight packing (MFMA B-frag order, bf16 hi/lo) ----------------
__global__ void k_packw(const float* __restrict__ w1, const float* __restrict__ w2,
                        short* __restrict__ w1h, short* __restrict__ w1l,
                        short* __restrict__ w2h, short* __restrict__ w2l) {
  int pg = blockIdx.x;
  for (int i = threadIdx.x; i < 4096; i += 256) {
    int t = i & 7, lane = (i >> 3) & 63, nt = (i >> 9) & 3, ks = i >> 11;
    int mr = lane & 15, kg = lane >> 4;
    int src = pg * 4096 + (ks * 32 + kg * 8 + t) * 64 + nt * 16 + mr;
    int dst = pg * 4096 + i;
    float v1 = w1[src]; short h1 = f2bf(v1);
    w1h[dst] = h1; w1l[dst] = f2bf(v1 - bf2f(h1));
    float v2 = w2[src]; short h2 = f2bf(v2);
    w2h[dst] = h2; w2l[dst] = f2bf(v2 - bf2f(h2));
  }
}
__global__ void k_packw_e(const float* __restrict__ w, short* __restrict__ wh, short* __restrict__ wl) {
  int set = blockIdx.x;
  for (int i = threadIdx.x; i < 8192; i += 256) {
    int t = i & 7, lane = (i >> 3) & 63, nt = (i >> 9) & 3, ks = i >> 11;
    int mr = lane & 15, kg = lane >> 4;
    int src = set * 8192 + (ks * 32 + kg * 8 + t) * 64 + nt * 16 + mr;
    int dst = set * 8192 + i;
    float v = w[src]; short h = f2bf(v);
    wh[dst] = h; wl[dst] = f2bf(v - bf2f(h));
  }
}

// ---------------- MFMA gate MLP (split-bf16), bf16 out in [g][n][d][b] ----------------
__global__ void __launch_bounds__(256) k_mlp_mfma(
    const float* __restrict__ in, const short* __restrict__ w1h, const short* __restrict__ w1l,
    const float* __restrict__ b1, const short* __restrict__ w2h, const short* __restrict__ w2l,
    const float* __restrict__ b2, int layer, unsigned short* __restrict__ out) {
  int g = blockIdx.y;
  int pg = g * kL + layer;
  int w = threadIdx.x >> 6, lane = threadIdx.x & 63;
  int mrow = lane & 15, kgrp = lane >> 4;
  int r0 = blockIdx.x * 64 + w * 16;
  __shared__ float hbuf[4][16][68];
  const float* xp = in + (size_t)(r0 + mrow) * 64 + kgrp * 8;
  bf16x8 a1h[2], a1l[2];
  #pragma unroll
  for (int ks = 0; ks < 2; ++ks) {
    #pragma unroll
    for (int t = 0; t < 8; ++t) {
      float v = xp[ks * 32 + t];
      short h = f2bf(v); a1h[ks][t] = h; a1l[ks][t] = f2bf(v - bf2f(h));
    }
  }
  const bf16x8* B1h = (const bf16x8*)(w1h + (size_t)pg * 4096);
  const bf16x8* B1l = (const bf16x8*)(w1l + (size_t)pg * 4096);
  #pragma unroll
  for (int nt = 0; nt < 4; ++nt) {
    f32x4 c = {0.f, 0.f, 0.f, 0.f};
    #pragma unroll
    for (int ks = 0; ks < 2; ++ks) {
      bf16x8 bh = B1h[(ks * 4 + nt) * 64 + lane];
      bf16x8 bl = B1l[(ks * 4 + nt) * 64 + lane];
      c = __builtin_amdgcn_mfma_f32_16x16x32_bf16(a1h[ks], bh, c, 0, 0, 0);
      c = __builtin_amdgcn_mfma_f32_16x16x32_bf16(a1h[ks], bl, c, 0, 0, 0);
      c = __builtin_amdgcn_mfma_f32_16x16x32_bf16(a1l[ks], bh, c, 0, 0, 0);
    }
    int col = nt * 16 + mrow;
    float bv = b1[pg * 64 + col];
    #pragma unroll
    for (int rg = 0; rg < 4; ++rg)
      hbuf[w][kgrp * 4 + rg][col] = fmaxf(c[rg] + bv, 0.f);
  }
  __syncthreads();
  bf16x8 a2h[2], a2l[2];
  #pragma unroll
  for (int ks = 0; ks < 2; ++ks) {
    #pragma unroll
    for (int t = 0; t < 8; ++t) {
      float v = hbuf[w][mrow][ks * 32 + kgrp * 8 + t];
      short h = f2bf(v); a2h[ks][t] = h; a2l[ks][t] = f2bf(v - bf2f(h));
    }
  }
  const bf16x8* B2h = (const bf16x8*)(w2h + (size_t)pg * 4096);
  const bf16x8* B2l = (const bf16x8*)(w2l + (size_t)pg * 4096);
  unsigned short* ob = out + (size_t)g * kB * kN * 64;
  #pragma unroll
  for (int nt = 0; nt < 4; ++nt) {
    f32x4 c = {0.f, 0.f, 0.f, 0.f};
    #pragma unroll
    for (int ks = 0; ks < 2; ++ks) {
      bf16x8 bh = B2h[(ks * 4 + nt) * 64 + lane];
      bf16x8 bl = B2l[(ks * 4 + nt) * 64 + lane];
      c = __builtin_amdgcn_mfma_f32_16x16x32_bf16(a2h[ks], bh, c, 0, 0, 0);
      c = __builtin_amdgcn_mfma_f32_16x16x32_bf16(a2h[ks], bl, c, 0, 0, 0);
      c = __builtin_amdgcn_mfma_f32_16x16x32_bf16(a2l[ks], bh, c, 0, 0, 0);
    }
    int col = nt * 16 + mrow;
    float bv = b2[pg * 64 + col];
    #pragma unroll
    for (int rg = 0; rg < 4; ++rg) {
      int grow = r0 + kgrp * 4 + rg;          // = b*kN + n
      int bb = grow / kN;
      int nn = grow - bb * kN;
      ob[(size_t)nn * 256 + col * 4 + bb] = (unsigned short)f2bf(c[rg] + bv);  // [n][d][b]
    }
  }
}

// ---------------- rel-gate MLP for entity phase: bf16 out in [j][r][d][b] ----------------
__global__ void __launch_bounds__(256) k_mlp_rel6(
    const float* __restrict__ in, fp p1w, fp p1b, fp p2w, fp p2b,
    unsigned short* __restrict__ out) {
  int j = blockIdx.y;
  int row = blockIdx.x * 4 + (threadIdx.x >> 6);   // = b*256 + r
  int lane = threadIdx.x & 63;
  fp W1 = p1w + (size_t)j * 4096;
  fp W2 = p2w + (size_t)j * 4096;
  float xv = in[(size_t)row * 64 + lane];
  float a = p1b[j * 64 + lane];
  float wbuf[8];
  #pragma unroll
  for (int kk = 0; kk < 64; kk += 8) {
    #pragma unroll
    for (int u = 0; u < 8; ++u) wbuf[u] = W1[(kk + u) * 64 + lane];
    #pragma unroll
    for (int u = 0; u < 8; ++u) a = fmaf(rdlane(xv, kk + u), wbuf[u], a);
  }
  a = fmaxf(a, 0.f);
  float c = p2b[j * 64 + lane];
  #pragma unroll
  for (int kk = 0; kk < 64; kk += 8) {
    #pragma unroll
    for (int u = 0; u < 8; ++u) wbuf[u] = W2[(kk + u) * 64 + lane];
    #pragma unroll
    for (int u = 0; u < 8; ++u) c = fmaf(rdlane(a, kk + u), wbuf[u], c);
  }
  int b = row >> 8, r = row & 255;
  out[((size_t)j * kR + r) * 256 + lane * 4 + b] = (unsigned short)f2bf(c);  // [r][d][b]
}

// ---------------- i=0 rel specials ----------------
__global__ void k_gate0(fp p1w, fp p1b, fp p2w, fp p2b, float* __restrict__ gate0) {
  int g = threadIdx.x >> 6, lane = threadIdx.x & 63;
  int pg = g * kL;
  float a = p1b[pg * 64 + lane];
  #pragma unroll
  for (int k = 0; k < 64; ++k) a += p1w[(size_t)pg * 4096 + k * 64 + lane];
  a = fmaxf(a, 0.f);
  float c = p2b[pg * 64 + lane];
  #pragma unroll
  for (int k = 0; k < 64; ++k)
    c = fmaf(rdlane(a, k), p2w[(size_t)pg * 4096 + k * 64 + lane], c);
  gate0[g * 64 + lane] = c;
}
__global__ void k_rel_agg0(const int* __restrict__ rel_start, const int2* __restrict__ rel_edges,
                           const int* __restrict__ batch, const float* __restrict__ gate0,
                           float* __restrict__ agg) {
  int wid = (blockIdx.x * blockDim.x + threadIdx.x) >> 6;
  int lane = threadIdx.x & 63;
  int g = wid >> 10, rem = wid & 1023, b = rem >> 8, r = rem & 255;
  int r0 = batch[b * kNEG * 3 + 2];
  const int* start = rel_start + g * 257;
  const int2* edges = rel_edges + (size_t)g * kER;
  int s0 = start[r], s1 = start[r + 1];
  int cnt = 0;
  for (int base = s0; base < s1; base += 64) {
    int e = base + lane;
    bool m = false;
    if (e < s1) m = (edges[e].x == r0);
    cnt += (int)__popcll(__ballot(m));
  }
  agg[(size_t)wid * 64 + lane] = gate0[g * 64 + lane] * (float)cnt + ((r == r0) ? 1.f : 0.f);
}

// ---------------- rel gather: block=(g,r), d-major interleave ----------------
__global__ void __launch_bounds__(256) k_gather_rel_all(
    const float* __restrict__ rxi, const unsigned short* __restrict__ gateN,
    const int* __restrict__ rel_start, const int2* __restrict__ rel_edges,
    const int* __restrict__ batch, float* __restrict__ agg) {
  int i = blockIdx.x;                  // 1024 = r*4 + g
  int g = i & 3, r = i >> 2;
  const unsigned short* gate = gateN + (size_t)g * kB * kN * 64;
  const int* start = rel_start + g * 257;
  const int2* edges = rel_edges + (size_t)g * kER;
  int w = threadIdx.x >> 6, lane = threadIdx.x & 63;
  int s0 = start[r], s1 = start[r + 1];
  int len = s1 - s0;
  int per = (len + 3) >> 2;
  int e0 = s0 + w * per, e1 = min(e0 + per, s1);
  float a0 = 0.f, a1 = 0.f, a2 = 0.f, a3 = 0.f;
  int2 se;
  if (e0 < e1) se = edges[e0];
  for (int e = e0; e < e1; ++e) {
    int2 cur = se;
    if (e + 1 < e1) se = edges[e + 1];
    float4 xv4 = *((const float4*)(rxi + (size_t)cur.x * 256) + lane);
    ushort4 gv4 = *((const ushort4*)(gate + (size_t)cur.y * 256) + lane);
    a0 = fmaf(xv4.x, bf2f_u(gv4.x), a0);
    a1 = fmaf(xv4.y, bf2f_u(gv4.y), a1);
    a2 = fmaf(xv4.z, bf2f_u(gv4.z), a2);
    a3 = fmaf(xv4.w, bf2f_u(gv4.w), a3);
  }
  __shared__ float red[4][4][64];
  red[w][0][lane] = a0; red[w][1][lane] = a1; red[w][2][lane] = a2; red[w][3][lane] = a3;
  __syncthreads();
  float a = red[0][w][lane] + red[1][w][lane] + red[2][w][lane] + red[3][w][lane];
  int r0b = batch[w * kNEG * 3 + 2];
  if (r == r0b) a += 1.0f;
  agg[(((size_t)g * kB + w) * kR + r) * 64 + lane] = a;
}

// ---------------- rel conv partial: grid (64, g) ----------------
__global__ void __launch_bounds__(256) k_conv_rel3(
    const float* __restrict__ rel_x, float* __restrict__ agg,
    fp rlw, fp rlb, fp rlns, fp rlnb, int layer) {
  int g = blockIdx.y;
  int pg = g * kL + layer;
  int wave = threadIdx.x >> 6, lane = threadIdx.x & 63;
  int row0 = blockIdx.x * 16 + wave * 4;
  const float* xp = rel_x + (size_t)row0 * 64 + lane;
  float* ap = agg + ((size_t)g * 1024 + row0) * 64 + lane;
  float x0 = xp[0], x1 = xp[64], x2 = xp[128], x3 = xp[192];
  float g0 = ap[0], g1 = ap[64], g2 = ap[128], g3 = ap[192];
  fp w1 = rlw + (size_t)pg * 8192;
  float bv = rlb[pg * 64 + lane];
  float o0 = bv, o1 = bv, o2 = bv, o3 = bv;
  float wbuf[8];
  #pragma unroll
  for (int kk = 0; kk < 128; kk += 8) {
    #pragma unroll
    for (int u = 0; u < 8; ++u) wbuf[u] = w1[(kk + u) * 64 + lane];
    #pragma unroll
    for (int u = 0; u < 8; ++u) {
      int k = kk + u; float w = wbuf[u];
      if (k < 64) {
        o0 = fmaf(rdlane(x0, k), w, o0); o1 = fmaf(rdlane(x1, k), w, o1);
        o2 = fmaf(rdlane(x2, k), w, o2); o3 = fmaf(rdlane(x3, k), w, o3);
      } else {
        o0 = fmaf(rdlane(g0, k - 64), w, o0); o1 = fmaf(rdlane(g1, k - 64), w, o1);
        o2 = fmaf(rdlane(g2, k - 64), w, o2); o3 = fmaf(rdlane(g3, k - 64), w, o3);
      }
    }
  }
  float s = rlns[pg * 64 + lane], t = rlnb[pg * 64 + lane];
  { float m = wave_sum64(o0) * (1.f/64.f); float c = o0 - m;
    float v = wave_sum64(c*c) * (1.f/64.f);
    ap[0] = fmaxf(c * rsqrtf(v + 1e-5f) * s + t, 0.f); }
  { float m = wave_sum64(o1) * (1.f/64.f); float c = o1 - m;
    float v = wave_sum64(c*c) * (1.f/64.f);
    ap[64] = fmaxf(c * rsqrtf(v + 1e-5f) * s + t, 0.f); }
  { float m = wave_sum64(o2) * (1.f/64.f); float c = o2 - m;
    float v = wave_sum64(c*c) * (1.f/64.f);
    ap[128] = fmaxf(c * rsqrtf(v + 1e-5f) * s + t, 0.f); }
  { float m = wave_sum64(o3) * (1.f/64.f); float c = o3 - m;
    float v = wave_sum64(c*c) * (1.f/64.f);
    ap[192] = fmaxf(c * rsqrtf(v + 1e-5f) * s + t, 0.f); }
}

// rel_x += sum_g y[g]; maintain d-major mirror rxi[r][d][b]
__global__ void k_sum_rel(float* __restrict__ rel_x, float* __restrict__ rxi,
                          const float* __restrict__ y) {
  int i = blockIdx.x * blockDim.x + threadIdx.x;   // 65536
  float v = rel_x[i] + y[i] + y[65536 + i] + y[131072 + i] + y[196608 + i];
  rel_x[i] = v;
  int d = i & 63, row = i >> 6;
  int b = row >> 8, r = row & 255;
  rxi[(size_t)r * 256 + d * 4 + b] = v;
}

// ---------------- ent gather: wave = node, 4 batches, d-major bf16 operands ----------------
template<bool FIRST>
__global__ void __launch_bounds__(256) k_ent_gather(
    const unsigned short* __restrict__ xbf_cur, const unsigned short* __restrict__ gateL,
    const int* __restrict__ start, const int2* __restrict__ edges,
    const float* __restrict__ q, const int* __restrict__ batch,
    float* __restrict__ agg) {
  int n = (blockIdx.x * blockDim.x + threadIdx.x) >> 6;
  if (n >= kN) return;
  int lane = threadIdx.x & 63;
  int h0[4]; float qv[4];
  #pragma unroll
  for (int b = 0; b < 4; ++b) { h0[b] = batch[b * kNEG * 3]; qv[b] = q[b * 64 + lane]; }
  float a0 = 0.f, a1 = 0.f, a2 = 0.f, a3 = 0.f;
  int s0 = start[n], s1 = start[n + 1];
  int2 se;
  if (s0 < s1) se = edges[s0];
  for (int e = s0; e < s1; ++e) {
    int2 cur = se;
    if (e + 1 < s1) se = edges[e + 1];
    ushort4 gv4 = *((const ushort4*)(gateL + (size_t)cur.y * 256) + lane);
    if (FIRST) {
      if (cur.x == h0[0]) a0 = fmaf(qv[0], bf2f_u(gv4.x), a0);
      if (cur.x == h0[1]) a1 = fmaf(qv[1], bf2f_u(gv4.y), a1);
      if (cur.x == h0[2]) a2 = fmaf(qv[2], bf2f_u(gv4.z), a2);
      if (cur.x == h0[3]) a3 = fmaf(qv[3], bf2f_u(gv4.w), a3);
    } else {
      ushort4 xv4 = *((const ushort4*)(xbf_cur + (size_t)cur.x * 256) + lane);
      a0 = fmaf(bf2f_u(xv4.x), bf2f_u(gv4.x), a0);
      a1 = fmaf(bf2f_u(xv4.y), bf2f_u(gv4.y), a1);
      a2 = fmaf(bf2f_u(xv4.z), bf2f_u(gv4.z), a2);
      a3 = fmaf(bf2f_u(xv4.w), bf2f_u(gv4.w), a3);
    }
  }
  if (n == h0[0]) a0 += qv[0];
  if (n == h0[1]) a1 += qv[1];
  if (n == h0[2]) a2 += qv[2];
  if (n == h0[3]) a3 += qv[3];
  float* ap = agg + (size_t)n * 64 + lane;
  ap[0] = a0; ap[640000] = a1; ap[1280000] = a2; ap[1920000] = a3;
}

// ---------------- ent conv via MFMA: y = x + relu(LN(concat(x,agg)@lw + lb)) ----------------
__global__ void __launch_bounds__(256) k_ent_conv_mfma(
    const float* __restrict__ xcur, const float* __restrict__ aggv,
    float* __restrict__ xnext, unsigned short* __restrict__ xbf_next,
    const short* __restrict__ wh, const short* __restrict__ wl, int set,
    fp lb, fp lns, fp lnb) {
  int w = threadIdx.x >> 6, lane = threadIdx.x & 63;
  int mrow = lane & 15, kgrp = lane >> 4;
  int r0 = blockIdx.x * 64 + w * 16;
  int arow = r0 + mrow;
  bf16x8 ah[4], al[4];
  #pragma unroll
  for (int ks = 0; ks < 4; ++ks) {
    const float* p = (ks < 2) ? (xcur + (size_t)arow * 64 + ks * 32 + kgrp * 8)
                              : (aggv + (size_t)arow * 64 + (ks - 2) * 32 + kgrp * 8);
    #pragma unroll
    for (int t = 0; t < 8; ++t) {
      float v = p[t];
      short h = f2bf(v); ah[ks][t] = h; al[ks][t] = f2bf(v - bf2f(h));
    }
  }
  const bf16x8* Bh = (const bf16x8*)(wh + (size_t)set * 8192);
  const bf16x8* Bl = (const bf16x8*)(wl + (size_t)set * 8192);
  float o[4][4];
  #pragma unroll
  for (int nt = 0; nt < 4; ++nt) {
    f32x4 c = {0.f, 0.f, 0.f, 0.f};
    #pragma unroll
    for (int ks = 0; ks < 4; ++ks) {
      bf16x8 bh = Bh[(ks * 4 + nt) * 64 + lane];
      bf16x8 bl = Bl[(ks * 4 + nt) * 64 + lane];
      c = __builtin_amdgcn_mfma_f32_16x16x32_bf16(ah[ks], bh, c, 0, 0, 0);
      c = __builtin_amdgcn_mfma_f32_16x16x32_bf16(ah[ks], bl, c, 0, 0, 0);
      c = __builtin_amdgcn_mfma_f32_16x16x32_bf16(al[ks], bh, c, 0, 0, 0);
    }
    float bv = lb[nt * 16 + mrow];
    #pragma unroll
    for (int rg = 0; rg < 4; ++rg) o[nt][rg] = c[rg] + bv;
  }
  float mean[4], varr[4];
  #pragma unroll
  for (int rg = 0; rg < 4; ++rg) {
    float p = o[0][rg] + o[1][rg] + o[2][rg] + o[3][rg];
    mean[rg] = group_sum16(p) * (1.f / 64.f);
    float d0 = o[0][rg] - mean[rg], d1 = o[1][rg] - mean[rg];
    float d2 = o[2][rg] - mean[rg], d3 = o[3][rg] - mean[rg];
    float vs = d0 * d0 + d1 * d1 + d2 * d2 + d3 * d3;
    varr[rg] = group_sum16(vs) * (1.f / 64.f);
  }
  #pragma unroll
  for (int nt = 0; nt < 4; ++nt) {
    int col = nt * 16 + mrow;
    float s = lns[col], tt = lnb[col];
    #pragma unroll
    for (int rg = 0; rg < 4; ++rg) {
      int grow = r0 + kgrp * 4 + rg;
      float xv = xcur[(size_t)grow * 64 + col];
      float y = xv + fmaxf((o[nt][rg] - mean[rg]) * rsqrtf(varr[rg] + 1e-5f) * s + tt, 0.f);
      xnext[(size_t)grow * 64 + col] = y;
      int bb = grow / kN;
      int nn = grow - bb * kN;
      xbf_next[(size_t)nn * 256 + col * 4 + bb] = (unsigned short)f2bf(y);
    }
  }
}

// ---------------- node_reps = concat(ent_x, q)@nmw + nmb ----------------
__global__ void __launch_bounds__(256) k_nodeup4(
    const float* __restrict__ x, const float* __restrict__ q,
    fp nmw, fp nmb, float* __restrict__ out) {
  int wid = (blockIdx.x * blockDim.x + threadIdx.x) >> 6;
  int lane = threadIdx.x & 63;
  int r0 = wid * 4;
  if (r0 >= kB * kN) return;
  int b = r0 / kN;
  const float* ip = x + (size_t)r0 * 64 + lane;
  float x0 = ip[0], x1 = ip[64], x2 = ip[128], x3 = ip[192];
  float qv = q[b * 64 + lane];
  float bv = nmb[lane];
  float c0 = bv, c1 = bv, c2 = bv, c3 = bv;
  float wbuf[4];
  #pragma unroll
  for (int kk = 0; kk < 64; kk += 4) {
    #pragma unroll
    for (int u = 0; u < 4; ++u) wbuf[u] = nmw[(kk + u) * 64 + lane];
    #pragma unroll
    for (int u = 0; u < 4; ++u) {
      int k = kk + u; float w = wbuf[u];
      c0 = fmaf(rdlane(x0, k), w, c0); c1 = fmaf(rdlane(x1, k), w, c1);
      c2 = fmaf(rdlane(x2, k), w, c2); c3 = fmaf(rdlane(x3, k), w, c3);
    }
  }
  float qa = 0.f;
  #pragma unroll
  for (int k = 0; k < 64; ++k)
    qa = fmaf(rdlane(qv, k), nmw[(64 + k) * 64 + lane], qa);
  float* op = out + (size_t)r0 * 64 + lane;
  op[0] = c0 + qa; op[64] = c1 + qa; op[128] = c2 + qa; op[192] = c3 + qa;
}

// ---------------- final scoring ----------------
__global__ void k_score(const float* __restrict__ entx, const float* __restrict__ q,
                        const int* __restrict__ batch,
                        fp m1w, fp m1b, fp m2w, fp m2b,
                        float* __restrict__ out) {
  int b = blockIdx.x / kNEG, n = blockIdx.x % kNEG;
  int t = batch[(b * kNEG + n) * 3 + 1];
  int j = threadIdx.x;
  __shared__ float gv[128];
  __shared__ float red[2];
  gv[j] = (j < 64) ? entx[((size_t)b * kN + t) * 64 + j] : q[b * 64 + (j - 64)];
  __syncthreads();
  float acc = m1b[j];
  #pragma unroll 16
  for (int k = 0; k < 128; ++k)
    acc = fmaf(gv[k], m1w[k * 128 + j], acc);
  float h = fmaxf(acc, 0.f) * m2w[j];
  h = wave_sum64(h);
  if ((j & 63) == 0) red[j >> 6] = h;
  __syncthreads();
  if (j == 0) out[b * kNEG + n] = red[0] + red[1] + m2b[0];
}

// ---------------- host ----------------
extern "C" void kernel_launch(void* const* d_in, const int* in_sizes, int n_in,
                              void* d_out, int out_size, void* d_ws, size_t ws_size,
                              hipStream_t stream) {
  const int* edge_src  = (const int*)d_in[0];
  const int* edge_dst  = (const int*)d_in[1];
  const int* edge_type = (const int*)d_in[2];
  const int* rel_src   = (const int*)d_in[3];
  const int* rel_dst   = (const int*)d_in[4];
  const int* rel_etype = (const int*)d_in[5];
  const int* batch     = (const int*)d_in[6];
  fp e1p1w = (fp)d_in[7],  e1p1b = (fp)d_in[8],  e1p2w = (fp)d_in[9],  e1p2b = (fp)d_in[10];
  fp e1lw  = (fp)d_in[11], e1lb  = (fp)d_in[12], e1lns = (fp)d_in[13], e1lnb = (fp)d_in[14];
  fp e2p1w = (fp)d_in[15], e2p1b = (fp)d_in[16], e2p2w = (fp)d_in[17], e2p2b = (fp)d_in[18];
  fp e2lw  = (fp)d_in[19], e2lb  = (fp)d_in[20], e2lns = (fp)d_in[21], e2lnb = (fp)d_in[22];
  fp e2m1w = (fp)d_in[23], e2m1b = (fp)d_in[24], e2m2w = (fp)d_in[25], e2m2b = (fp)d_in[26];
  fp rp1w  = (fp)d_in[27], rp1b  = (fp)d_in[28], rp2w  = (fp)d_in[29], rp2b  = (fp)d_in[30];
  fp rlw   = (fp)d_in[31], rlb   = (fp)d_in[32], rlns  = (fp)d_in[33], rlnb  = (fp)d_in[34];
  fp nmw   = (fp)d_in[35], nmb   = (fp)d_in[36];

  float* ws = (float*)d_ws;
  float* rel_x     = ws;                           // 65,536
  float* q         = rel_x + 65536;                // 256
  float* gate0     = q + 256;                      // 256
  float* rxi       = gate0 + 256;                  // 65,536 ([r][d][b])
  float* rel_agg   = rxi + 65536;                  // 262,144
  float* node_reps = rel_agg + 262144;             // 2,560,000
  float* ent_xa    = node_reps + 2560000;          // 2,560,000
  float* ent_xb    = ent_xa + 2560000;             // 2,560,000
  float* ent_agg   = ent_xb + 2560000;             // 2,560,000 ([b][n][d])
  unsigned short* gateR6 = (unsigned short*)(ent_agg + 2560000); // 393,216 ([j][r][d][b])
  unsigned short* gateN  = gateR6 + 393216;        // 10,240,000 ([g][n][d][b])
  unsigned short* ent_ba = gateN + 10240000;       // 2,560,000 ([n][d][b])
  unsigned short* ent_bb = ent_ba + 2560000;       // 2,560,000
  int*   iws       = (int*)(ent_bb + 2560000);
  int2*  ent_edges = (int2*)iws;                   // 400,000 ints
  int2*  rel_edges = (int2*)(iws + 400000);        // 640,000 ints
  int*   ent_cnt   = iws + 400000 + 640000;        // 10,000
  int*   ent_start = ent_cnt + 10000;              // 10,001
  int*   ent_cur   = ent_start + 10001;            // 10,001
  int*   rel_cnt   = ent_cur + 10001;              // 1,024
  int*   rel_start = rel_cnt + 1024;               // 1,028
  int*   rel_cur   = rel_start + 1028;             // 1,028
  short* w1hp      = (short*)(rel_cur + 1028 + 2); // 98,304 shorts each
  short* w1lp      = w1hp + 98304;
  short* w2hp      = w1lp + 98304;
  short* w2lp      = w2hp + 98304;
  short* elwh      = w2lp + 98304;                 // 12*8192
  short* elwl      = elwh + 98304;

  const int nZero = 10000 + 10001 + 10001 + 1024;
  // ---- CSR build + weight packing ----
  k_zero_i<<<(nZero + 255) / 256, 256, 0, stream>>>(ent_cnt, nZero);
  k_hist<<<(kE + 255) / 256, 256, 0, stream>>>(edge_dst, kE, ent_cnt);
  k_hist_rel_lds<<<dim3(10, 4), 256, 0, stream>>>(rel_dst, rel_cnt);
  k_scan_multi<<<1, 256, 0, stream>>>(ent_cnt, ent_start, ent_cur, 10000, 0, 0);
  k_scan_multi<<<4, 256, 0, stream>>>(rel_cnt, rel_start, rel_cur, 256, 256, 257);
  k_fill_csr<<<(kE + 255) / 256, 256, 0, stream>>>(edge_src, edge_dst, edge_type, kE, ent_cur, ent_edges);
  k_fill_rel_lds<<<dim3(10, 4), 256, 0, stream>>>(rel_src, rel_dst, rel_etype, rel_cur, rel_edges);
  k_packw<<<24, 256, 0, stream>>>(rp1w, rp2w, w1hp, w1lp, w2hp, w2lp);
  k_packw_e<<<6, 256, 0, stream>>>(e1lw, elwh, elwl);
  k_packw_e<<<6, 256, 0, stream>>>(e2lw, elwh + 6 * 8192, elwl + 6 * 8192);

  // ---- rel_x = one-hot boundary ----
  k_fill<<<256, 256, 0, stream>>>(rel_x, 0.f, kB * kR * kD);
  k_add_row<<<1, 256, 0, stream>>>(rel_x, batch);

  // ---- i = 0 (node_reps == ones) ----
  k_gate0<<<1, 256, 0, stream>>>(rp1w, rp1b, rp2w, rp2b, gate0);
  k_rel_agg0<<<1024, 256, 0, stream>>>(rel_start, rel_edges, batch, gate0, rel_agg);
  k_conv_rel3<<<dim3(64, 4), 256, 0, stream>>>(rel_x, rel_agg, rlw, rlb, rlns, rlnb, 0);
  k_sum_rel<<<256, 256, 0, stream>>>(rel_x, rxi, rel_agg);

  // ---- entity_bf with e1 params -> node_reps ----
  k_get_q<<<1, 256, 0, stream>>>(q, rel_x, batch);
  k_mlp_rel6<<<dim3(256, 6), 256, 0, stream>>>(rel_x, e1p1w, e1p1b, e1p2w, e1p2b, gateR6);
  k_fill<<<2048, 256, 0, stream>>>(ent_xa, 0.f, kB * kN * kD);
  k_add_row_ent<<<1, 256, 0, stream>>>(ent_xa, batch, q);
  {
    float* cur = ent_xa; float* nxt = ent_xb;
    unsigned short* bcur = ent_ba; unsigned short* bnxt = ent_bb;
    for (int j = 0; j < kL; ++j) {
      const unsigned short* gL = gateR6 + (size_t)j * kR * 256;
      if (j == 0)
        k_ent_gather<true><<<2500, 256, 0, stream>>>(bcur, gL, ent_start, ent_edges, q, batch, ent_agg);
      else
        k_ent_gather<false><<<2500, 256, 0, stream>>>(bcur, gL, ent_start, ent_edges, q, batch, ent_agg);
      k_ent_conv_mfma<<<625, 256, 0, stream>>>(cur, ent_agg, nxt, bnxt, elwh, elwl, j,
          e1lb + (size_t)j * 64, e1lns + (size_t)j * 64, e1lnb + (size_t)j * 64);
      float* tf = cur; cur = nxt; nxt = tf;
      unsigned short* tb = bcur; bcur = bnxt; bnxt = tb;
    }
    k_nodeup4<<<2500, 256, 0, stream>>>(cur, q, nmw, nmb, node_reps);
  }

  // ---- i = 1..5 ----
  for (int i = 1; i < kL; ++i) {
    k_mlp_mfma<<<dim3(625, 4), 256, 0, stream>>>(node_reps, w1hp, w1lp, rp1b, w2hp, w2lp, rp2b, i, gateN);
    k_gather_rel_all<<<1024, 256, 0, stream>>>(rxi, gateN, rel_start, rel_edges, batch, rel_agg);
    k_conv_rel3<<<dim3(64, 4), 256, 0, stream>>>(rel_x, rel_agg, rlw, rlb, rlns, rlnb, i);
    k_sum_rel<<<256, 256, 0, stream>>>(rel_x, rxi, rel_agg);
  }

  // ---- entity_bf with e2 params + scoring ----
  k_get_q<<<1, 256, 0, stream>>>(q, rel_x, batch);
  k_mlp_rel6<<<dim3(256, 6), 256, 0, stream>>>(rel_x, e2p1w, e2p1b, e2p2w, e2p2b, gateR6);
  k_fill<<<2048, 256, 0, stream>>>(ent_xa, 0.f, kB * kN * kD);
  k_add_row_ent<<<1, 256, 0, stream>>>(ent_xa, batch, q);
  {
    float* cur = ent_xa; float* nxt = ent_xb;
    unsigned short* bcur = ent_ba; unsigned short* bnxt = ent_bb;
    for (int j = 0; j < kL; ++j) {
      const unsigned short* gL = gateR6 + (size_t)j * kR * 256;
      if (j == 0)
        k_ent_gather<true><<<2500, 256, 0, stream>>>(bcur, gL, ent_start, ent_edges, q, batch, ent_agg);
      else
        k_ent_gather<false><<<2500, 256, 0, stream>>>(bcur, gL, ent_start, ent_edges, q, batch, ent_agg);
      k_ent_conv_mfma<<<625, 256, 0, stream>>>(cur, ent_agg, nxt, bnxt, elwh, elwl, 6 + j,
          e2lb + (size_t)j * 64, e2lns + (size_t)j * 64, e2lnb + (size_t)j * 64);
      float* tf = cur; cur = nxt; nxt = tf;
      unsigned short* tb = bcur; bcur = bnxt; bnxt = tb;
    }
    k_score<<<kB * kNEG, 128, 0, stream>>>(cur, q, batch, e2m1w, e2m1b, e2m2w, e2m2b, (float*)d_out);
  }
}